// Round 1
// baseline (1422.200 us; speedup 1.0000x reference)
//
#include <hip/hip_runtime.h>
#include <math.h>

#define DIM 7
#define HID 128
#define CHOL 28
#define NBLK_A 1024
#define ITERS_A 32
#define NBLK_B 1024
#define ITERS_B 8

__device__ __forceinline__ float sp_f(float x){ return fmaxf(x,0.f) + log1pf(expf(-fabsf(x))); }
__device__ __forceinline__ float sig_f(float x){ return 1.f/(1.f+expf(-x)); }

// ---------------- Kernel A: mass matrix M, Jacobian (fwd-mode), Coriolis, gradV ----------------
// tau_A[i] = (L u)[i] + (dLs w)[i] + (L vs)[i] - w.v_i + gradV[i]
//   w = L^T dq, u = L^T ddq, dLs = sum_j dq_j dL_j, vs = dLs^T dq, v_i = dL_i^T dq
__global__ __launch_bounds__(256, 4) void kernA(
    const float* __restrict__ q, const float* __restrict__ dq, const float* __restrict__ ddq,
    const float* __restrict__ mW1, const float* __restrict__ mb1,
    const float* __restrict__ mW2, const float* __restrict__ mb2,
    const float* __restrict__ mW3, const float* __restrict__ mb3,
    const float* __restrict__ pW1, const float* __restrict__ pb1, const float* __restrict__ pw2,
    float* __restrict__ out)
{
  __shared__ float b1s[HID], b2s[HID], pb1s[HID], spw2s[HID], b3s[CHOL];
  __shared__ __align__(16) float AB[4][HID][8];   // per-wave: rows = [fwd, tan0..tan6]
  __shared__ float raw8[4][8][CHOL];
  __shared__ float sb[4][HID];                    // sigmoid(zp)*softplus(pw2)
  __shared__ float Lbs[4][CHOL], dLss[4][CHOL], dfs[4][CHOL], gvp[4][CHOL];
  __shared__ float wbs[4][DIM], ubs[4][DIM], vss[4][DIM];

  const int tid  = threadIdx.x;
  const int w    = tid >> 6;
  const int lane = tid & 63;

  for (int i = tid; i < HID; i += 256) {
    b1s[i] = mb1[i]; b2s[i] = mb2[i]; pb1s[i] = pb1[i]; spw2s[i] = sp_f(pw2[i]);
  }
  if (tid < CHOL) b3s[tid] = mb3[tid];
  __syncthreads();

  const int n0 = lane, n1 = lane + 64;
  const int r3 = lane / 7;            // layer-3 row (valid for lane<56); also gv chunk (lane<28)
  const int p3 = lane - r3 * 7;       // layer-3 col group; also gv row index
  const int ocol = 4 * p3;

  for (int it = 0; it < ITERS_A; ++it) {
    const int elem = (it * NBLK_A + (int)blockIdx.x) * 4 + w;
    const long b7 = (long)elem * DIM;
    float qv[DIM], dqv[DIM], ddqv[DIM];
#pragma unroll
    for (int j = 0; j < DIM; ++j) { qv[j] = q[b7+j]; dqv[j] = dq[b7+j]; ddqv[j] = ddq[b7+j]; }

    // ---- phase 1: layer 1 + tangent seeds + potential hidden
#pragma unroll
    for (int half = 0; half < 2; ++half) {
      const int n = lane + 64 * half;
      float w1v[DIM];
      float z1 = b1s[n];
      float zp = pb1s[n];
#pragma unroll
      for (int j = 0; j < DIM; ++j) {
        w1v[j] = mW1[j*HID + n];
        z1 = fmaf(qv[j], w1v[j], z1);
        zp = fmaf(qv[j], pW1[j*HID + n], zp);
      }
      const float h1 = tanhf(z1);
      const float g1 = 1.f - h1*h1;
      AB[w][n][0] = h1;
#pragma unroll
      for (int j = 0; j < DIM; ++j) AB[w][n][1+j] = g1 * w1v[j];
      sb[w][n] = sig_f(zp) * spw2s[n];
    }
    __syncthreads();

    // ---- phase 2: layer 2, 8 rows x 2 cols per lane
    float acc[8][2];
#pragma unroll
    for (int r = 0; r < 8; ++r) { acc[r][0] = 0.f; acc[r][1] = 0.f; }
#pragma unroll 4
    for (int m = 0; m < HID; ++m) {
      const float4 a0 = *(const float4*)(&AB[w][m][0]);
      const float4 a1 = *(const float4*)(&AB[w][m][4]);
      const float wa  = mW2[m*HID + n0];
      const float wb2 = mW2[m*HID + n1];
      acc[0][0]=fmaf(a0.x,wa,acc[0][0]); acc[0][1]=fmaf(a0.x,wb2,acc[0][1]);
      acc[1][0]=fmaf(a0.y,wa,acc[1][0]); acc[1][1]=fmaf(a0.y,wb2,acc[1][1]);
      acc[2][0]=fmaf(a0.z,wa,acc[2][0]); acc[2][1]=fmaf(a0.z,wb2,acc[2][1]);
      acc[3][0]=fmaf(a0.w,wa,acc[3][0]); acc[3][1]=fmaf(a0.w,wb2,acc[3][1]);
      acc[4][0]=fmaf(a1.x,wa,acc[4][0]); acc[4][1]=fmaf(a1.x,wb2,acc[4][1]);
      acc[5][0]=fmaf(a1.y,wa,acc[5][0]); acc[5][1]=fmaf(a1.y,wb2,acc[5][1]);
      acc[6][0]=fmaf(a1.z,wa,acc[6][0]); acc[6][1]=fmaf(a1.z,wb2,acc[6][1]);
      acc[7][0]=fmaf(a1.w,wa,acc[7][0]); acc[7][1]=fmaf(a1.w,wb2,acc[7][1]);
    }
    __syncthreads();   // all AB reads done before overwrite

    // ---- phase 3: tanh + restage B rows (h2, h2dot_j)
#pragma unroll
    for (int half = 0; half < 2; ++half) {
      const int n = lane + 64 * half;
      const float h2 = tanhf(acc[0][half] + b2s[n]);
      const float g2 = 1.f - h2*h2;
      AB[w][n][0] = h2;
#pragma unroll
      for (int j = 0; j < DIM; ++j) AB[w][n][1+j] = g2 * acc[1+j][half];
    }
    __syncthreads();

    // ---- phase 4: layer 3 (8 rows x 28 cols): 56 lanes, 4 cols each (float4 W3 rows)
    if (lane < 56) {
      float r0=0.f, r1=0.f, r2=0.f, rr3=0.f;
#pragma unroll 4
      for (int m = 0; m < HID; ++m) {
        const float bv = AB[w][m][r3];
        const float4 w3 = *(const float4*)(&mW3[m*CHOL + ocol]);
        r0=fmaf(bv,w3.x,r0); r1=fmaf(bv,w3.y,r1); r2=fmaf(bv,w3.z,r2); rr3=fmaf(bv,w3.w,rr3);
      }
      if (r3 == 0) { r0+=b3s[ocol]; r1+=b3s[ocol+1]; r2+=b3s[ocol+2]; rr3+=b3s[ocol+3]; }
      raw8[w][r3][ocol+0]=r0; raw8[w][r3][ocol+1]=r1;
      raw8[w][r3][ocol+2]=r2; raw8[w][r3][ocol+3]=rr3;
    }
    __syncthreads();

    // ---- phase 5a: Cholesky entries, dLs, gradV partials (lane<28)
    if (lane < CHOL) {
      const float e0 = raw8[w][0][lane];
      const bool dg = (lane==0)|(lane==2)|(lane==5)|(lane==9)|(lane==14)|(lane==20)|(lane==27);
      const float Lv = dg ? sp_f(e0) : e0;
      const float df = dg ? sig_f(e0) : 1.f;
      float s_ = 0.f;
#pragma unroll
      for (int j = 0; j < DIM; ++j) s_ = fmaf(dqv[j], raw8[w][1+j][lane], s_);
      Lbs[w][lane] = Lv; dfs[w][lane] = df; dLss[w][lane] = df * s_;
      // gradV partial: row i=p3, chunk r3 (32 hidden units)
      float gp = 0.f;
      const int nb = 32 * r3;
#pragma unroll 8
      for (int nn = 0; nn < 32; ++nn) gp = fmaf(pW1[p3*HID + nb + nn], sb[w][nb + nn], gp);
      gvp[w][lane] = gp;
    }
    __syncthreads();

    // ---- phase 5b: columns w,u,vs (lane<7, c=lane)
    if (lane < DIM) {
      const int c = lane;
      float wv=0.f, uv=0.f, vv=0.f;
#pragma unroll
      for (int r = 0; r < DIM; ++r) {
        if (r >= c) {
          const int id = r*(r+1)/2 + c;
          const float Lrc = Lbs[w][id];
          wv = fmaf(Lrc, dqv[r], wv);
          uv = fmaf(Lrc, ddqv[r], uv);
          vv = fmaf(dLss[w][id], dqv[r], vv);
        }
      }
      wbs[w][c]=wv; ubs[w][c]=uv; vss[w][c]=vv;
    }
    __syncthreads();

    // ---- phase 5c: final tau row i (lane<7)
    if (lane < DIM) {
      const int i = lane;
      float t12 = 0.f;
#pragma unroll
      for (int c = 0; c < DIM; ++c) {
        if (c <= i) {
          const int id = i*(i+1)/2 + c;
          t12 = fmaf(Lbs[w][id], ubs[w][c] + vss[w][c], t12);
          t12 = fmaf(dLss[w][id], wbs[w][c], t12);
        }
      }
      float t3 = 0.f;
      const int TR[CHOL]={0,1,1,2,2,2,3,3,3,3,4,4,4,4,4,5,5,5,5,5,5,6,6,6,6,6,6,6};
      const int TC[CHOL]={0,0,1,0,1,2,0,1,2,3,0,1,2,3,4,0,1,2,3,4,5,0,1,2,3,4,5,6};
#pragma unroll
      for (int t = 0; t < CHOL; ++t) {
        t3 = fmaf(raw8[w][1+i][t]*dfs[w][t], dqv[TR[t]]*wbs[w][TC[t]], t3);
      }
      const float gv = gvp[w][i] + gvp[w][7+i] + gvp[w][14+i] + gvp[w][21+i];
      out[b7 + i] = t12 - t3 + gv;
    }
    __syncthreads();
  }
}

// ---------------- Kernel B: damping D(q,dq), tau += L_D (L_D^T dq) ----------------
__global__ __launch_bounds__(256, 4) void kernB(
    const float* __restrict__ q, const float* __restrict__ dq,
    const float* __restrict__ dW1, const float* __restrict__ db1,
    const float* __restrict__ dW2, const float* __restrict__ db2,
    const float* __restrict__ dW3, const float* __restrict__ db3,
    float* __restrict__ out)
{
  __shared__ float b1s[HID], b2s[HID], b3s[CHOL];
  __shared__ float A1[4][4][HID];
  __shared__ float rawD[4][4][CHOL];
  __shared__ float LbD[4][4][CHOL];
  __shared__ float wdb[4][4][DIM];

  const int tid = threadIdx.x, w = tid >> 6, lane = tid & 63;
  for (int i = tid; i < HID; i += 256) { b1s[i] = db1[i]; b2s[i] = db2[i]; }
  if (tid < CHOL) b3s[tid] = db3[tid];
  __syncthreads();

  const int n0 = lane, n1 = lane + 64;
  const int e3 = lane >> 4;
  const int s3 = lane & 15;

  for (int it = 0; it < ITERS_B; ++it) {
    const int ebase = (it * NBLK_B + (int)blockIdx.x) * 16 + w * 4;

    // phase 1: layer 1 (input = [q, dq], 14 dims)
#pragma unroll
    for (int e = 0; e < 4; ++e) {
      const long b7 = (long)(ebase + e) * DIM;
      float xv[2*DIM];
#pragma unroll
      for (int j = 0; j < DIM; ++j) { xv[j] = q[b7+j]; xv[DIM+j] = dq[b7+j]; }
#pragma unroll
      for (int half = 0; half < 2; ++half) {
        const int n = lane + 64 * half;
        float z1 = b1s[n];
#pragma unroll
        for (int j = 0; j < 2*DIM; ++j) z1 = fmaf(xv[j], dW1[j*HID + n], z1);
        A1[w][e][n] = tanhf(z1);
      }
    }
    __syncthreads();

    // phase 2: layer 2
    float acc[4][2];
#pragma unroll
    for (int e = 0; e < 4; ++e) { acc[e][0] = 0.f; acc[e][1] = 0.f; }
#pragma unroll 4
    for (int m = 0; m < HID; ++m) {
      const float wa = dW2[m*HID + n0], wb2 = dW2[m*HID + n1];
#pragma unroll
      for (int e = 0; e < 4; ++e) {
        const float av = A1[w][e][m];
        acc[e][0] = fmaf(av, wa, acc[e][0]);
        acc[e][1] = fmaf(av, wb2, acc[e][1]);
      }
    }
    __syncthreads();

    // phase 3: tanh, restage h2
#pragma unroll
    for (int e = 0; e < 4; ++e) {
#pragma unroll
      for (int half = 0; half < 2; ++half) {
        const int n = lane + 64 * half;
        A1[w][e][n] = tanhf(acc[e][half] + b2s[n]);
      }
    }
    __syncthreads();

    // phase 4: layer 3 — 16 lanes per element, outputs s3 and s3+16
    {
      float r0 = 0.f, r1 = 0.f;
      const bool two = (s3 < 12);
#pragma unroll 4
      for (int m = 0; m < HID; ++m) {
        const float bv = A1[w][e3][m];
        r0 = fmaf(bv, dW3[m*CHOL + s3], r0);
        if (two) r1 = fmaf(bv, dW3[m*CHOL + s3 + 16], r1);
      }
      rawD[w][e3][s3] = r0 + b3s[s3];
      if (two) rawD[w][e3][s3+16] = r1 + b3s[s3+16];
    }
    __syncthreads();

    // phase 5: build L (softplus diagonal)
#pragma unroll
    for (int k = 0; k < 2; ++k) {
      const int t = s3 + 16*k;
      if (t < CHOL) {
        const float e0 = rawD[w][e3][t];
        const bool dg = (t==0)|(t==2)|(t==5)|(t==9)|(t==14)|(t==20)|(t==27);
        LbD[w][e3][t] = dg ? sp_f(e0) : e0;
      }
    }
    __syncthreads();

    // phase 6: wd = L^T dq
    if (s3 < DIM) {
      const long b7 = (long)(ebase + e3) * DIM;
      const int c = s3;
      float wv = 0.f;
#pragma unroll
      for (int r = 0; r < DIM; ++r) {
        if (r >= c) wv = fmaf(LbD[w][e3][r*(r+1)/2 + c], dq[b7 + r], wv);
      }
      wdb[w][e3][c] = wv;
    }
    __syncthreads();

    // phase 7: tau += L wd
    if (s3 < DIM) {
      const long b7 = (long)(ebase + e3) * DIM;
      const int i = s3;
      float td = 0.f;
#pragma unroll
      for (int c = 0; c < DIM; ++c) {
        if (c <= i) td = fmaf(LbD[w][e3][i*(i+1)/2 + c], wdb[w][e3][c], td);
      }
      out[b7 + i] += td;
    }
    __syncthreads();
  }
}

extern "C" void kernel_launch(void* const* d_in, const int* in_sizes, int n_in,
                              void* d_out, int out_size, void* d_ws, size_t ws_size,
                              hipStream_t stream) {
  const float* q   = (const float*)d_in[0];
  const float* dq  = (const float*)d_in[1];
  const float* ddq = (const float*)d_in[2];
  const float* mW1 = (const float*)d_in[3];
  const float* mb1 = (const float*)d_in[4];
  const float* mW2 = (const float*)d_in[5];
  const float* mb2 = (const float*)d_in[6];
  const float* mW3 = (const float*)d_in[7];
  const float* mb3 = (const float*)d_in[8];
  const float* dW1 = (const float*)d_in[9];
  const float* db1 = (const float*)d_in[10];
  const float* dW2 = (const float*)d_in[11];
  const float* db2 = (const float*)d_in[12];
  const float* dW3 = (const float*)d_in[13];
  const float* db3 = (const float*)d_in[14];
  const float* pW1 = (const float*)d_in[15];
  const float* pb1 = (const float*)d_in[16];
  const float* pw2 = (const float*)d_in[17];
  float* out = (float*)d_out;

  hipLaunchKernelGGL(kernA, dim3(NBLK_A), dim3(256), 0, stream,
                     q, dq, ddq, mW1, mb1, mW2, mb2, mW3, mb3, pW1, pb1, pw2, out);
  hipLaunchKernelGGL(kernB, dim3(NBLK_B), dim3(256), 0, stream,
                     q, dq, dW1, db1, dW2, db2, dW3, db3, out);
}

// Round 6
// 825.271 us; speedup vs baseline: 1.7233x; 1.7233x over previous
//
#include <hip/hip_runtime.h>

#define DIM 7
#define HID 128
#define CHOL 28

#define GRID_A 2048
#define ITER_A 16          // 2048 blocks * 4 elem * 16 iter = 131072
#define NBLK_B 1024
#define ITERS_B 8

typedef float    f32x4  __attribute__((ext_vector_type(4)));
typedef short    bf16x8 __attribute__((ext_vector_type(8)));
typedef unsigned uint4v __attribute__((ext_vector_type(4)));

__device__ __forceinline__ float tanh_f(float x){ float e=__expf(2.f*x); return 1.f - 2.f/(e+1.f); }
__device__ __forceinline__ float sig_f(float x){ return 1.f/(1.f+__expf(-x)); }
__device__ __forceinline__ float sp_f(float x){ return fmaxf(x,0.f) + __logf(1.f+__expf(-fabsf(x))); }

__device__ __forceinline__ unsigned short f2b(float v){
  unsigned u = __float_as_uint(v);
  u += 0x7FFFu + ((u>>16)&1u);          // RNE to bf16
  return (unsigned short)(u>>16);
}
__device__ __forceinline__ bf16x8 as_bf(uint4v u){ union { uint4v a; bf16x8 f; } x; x.a=u; return x.f; }

// ---- ws layout (u32): [0,8192) W2frag ; [8192,10240) W3frag
// frag order: u32 idx = (frag_id*64 + lane)*4 + i2 ; B[k][col], k = 32s+8*(l>>4)+2*i2(+1), col = 16t+(l&15)
// (A-frags use the SAME (group,elem)->k map, so layer-2/3 are correct for any HW intra-lane k order.)
__global__ void setup_frags(const float* __restrict__ mW2, const float* __restrict__ mW3,
                            unsigned* __restrict__ ws){
  int idx = blockIdx.x*256 + threadIdx.x;
  if (idx < 8192) {
    int i2 = idx&3, f = idx>>2, l = f&63, st = f>>6;
    int s = st>>3, t = st&7;
    int k = 32*s + 8*(l>>4) + 2*i2, col = 16*t + (l&15);
    unsigned short lo = f2b(mW2[k*HID+col]), hi = f2b(mW2[(k+1)*HID+col]);
    ws[idx] = (unsigned)lo | ((unsigned)hi<<16);
  } else if (idx < 10240) {
    int j = idx-8192; int i2=j&3, f=j>>2, l=f&63, st=f>>6;
    int s = st>>1, t = st&1;
    int k = 32*s + 8*(l>>4) + 2*i2, col = 16*t + (l&15);
    float v0 = (col<CHOL) ? mW3[k*CHOL+col] : 0.f;
    float v1 = (col<CHOL) ? mW3[(k+1)*CHOL+col] : 0.f;
    ws[idx] = (unsigned)f2b(v0) | ((unsigned)f2b(v1)<<16);
  }
}

// ---------------- Kernel A: MFMA version ----------------
// 1 wave/block, 4 elements/iter. Two 16x128 A tiles: rows 8e..8e+7 = [fwd, tan0..6] of element e.
// Abuf layout: [mt][row][k] bf16, with 16B-block XOR swizzle: k-block kb stored at kb ^ (row&7).
__global__ __launch_bounds__(64, 2) void kernA(
    const float* __restrict__ q, const float* __restrict__ dq, const float* __restrict__ ddq,
    const float* __restrict__ mW1, const float* __restrict__ mb1,
    const float* __restrict__ mb2, const float* __restrict__ mb3,
    const float* __restrict__ pW1, const float* __restrict__ pb1, const float* __restrict__ pw2,
    const unsigned* __restrict__ ws, float* __restrict__ out)
{
  __shared__ __align__(16) unsigned short Abuf[2][16][HID];  // 8KB, reused for A'
  __shared__ float sbf[4][HID+8];                            // sigmoid(zp)*softplus(pw2), padded
  __shared__ float pW1s[DIM][HID+8];                         // pW1 staged, padded
  __shared__ float2 hg2[4][HID];                             // {h2, g2} per [elem][col]
  __shared__ float rawb[4][8][CHOL];
  __shared__ float b2s[HID];
  __shared__ float b3s[CHOL];
  __shared__ float Lbs[4][CHOL], dLss[4][CHOL], dfs[4][CHOL];
  __shared__ float gvp2[4][14];
  __shared__ float wbs[4][DIM], ubs[4][DIM], vss[4][DIM];

  const int lane = threadIdx.x;
  const int g4 = lane>>4, c = lane&15;
  const int R = lane&15, r7 = lane&7;

  b2s[lane] = mb2[lane]; b2s[lane+64] = mb2[lane+64];
  if (lane < CHOL) b3s[lane] = mb3[lane];
  for (int idx = lane; idx < DIM*HID; idx += 64) pW1s[idx>>7][idx&127] = pW1[idx];

  // iteration-invariant weights in registers
  float w1v0[DIM], w1v1[DIM], pw1v0[DIM], pw1v1[DIM];
#pragma unroll
  for (int j=0;j<DIM;++j){
    w1v0[j]=mW1[j*HID+lane];  w1v1[j]=mW1[j*HID+lane+64];
    pw1v0[j]=pW1[j*HID+lane]; pw1v1[j]=pW1[j*HID+lane+64];
  }
  const float b1v0=mb1[lane], b1v1=mb1[lane+64];
  const float pbv0=pb1[lane], pbv1=pb1[lane+64];
  const float sp0=sp_f(pw2[lane]), sp1=sp_f(pw2[lane+64]);

  const uint4v* __restrict__ W2f = (const uint4v*)ws;
  const uint4v* __restrict__ W3f = (const uint4v*)(ws + 8192);

  __syncthreads();

  for (int it=0; it<ITER_A; ++it){
    const int ebase = (it*GRID_A + (int)blockIdx.x)*4;

    // ---- phase 1: layer 1 + tangent seeds + sb
    const int kb0 = lane>>3, ko = lane&7;
#pragma unroll
    for (int e=0;e<4;++e){
      const float* qp = q + (long)(ebase+e)*DIM;
      float qv[DIM];
#pragma unroll
      for (int j=0;j<DIM;++j) qv[j]=qp[j];
      const int mt = e>>1, R0 = 8*(e&1);
      {
        float z1=b1v0, zp=pbv0;
#pragma unroll
        for (int j=0;j<DIM;++j){ z1=fmaf(qv[j],w1v0[j],z1); zp=fmaf(qv[j],pw1v0[j],zp); }
        float h1=tanh_f(z1), g1=1.f-h1*h1;
        Abuf[mt][R0][8*kb0 + ko] = f2b(h1);                      // row&7==0: kb^0
#pragma unroll
        for (int j=0;j<DIM;++j)
          Abuf[mt][R0+1+j][8*(kb0^(1+j)) + ko] = f2b(g1*w1v0[j]);
        sbf[e][lane] = sig_f(zp)*sp0;
      }
      {
        float z1=b1v1, zp=pbv1;
#pragma unroll
        for (int j=0;j<DIM;++j){ z1=fmaf(qv[j],w1v1[j],z1); zp=fmaf(qv[j],pw1v1[j],zp); }
        float h1=tanh_f(z1), g1=1.f-h1*h1;
        const int kb1 = kb0+8;
        Abuf[mt][R0][8*kb1 + ko] = f2b(h1);
#pragma unroll
        for (int j=0;j<DIM;++j)
          Abuf[mt][R0+1+j][8*(kb1^(1+j)) + ko] = f2b(g1*w1v1[j]);
        sbf[e][lane+64] = sig_f(zp)*sp1;
      }
    }
    __syncthreads();

    // ---- layer 2 MFMA: [32 x 128] @ [128 x 128]
    f32x4 acc2[2][8];
#pragma unroll
    for (int a=0;a<2;++a)
#pragma unroll
      for (int b=0;b<8;++b) acc2[a][b] = f32x4{0.f,0.f,0.f,0.f};
#pragma unroll
    for (int s=0;s<4;++s){
      const int blk = 8*((4*s+g4)^r7);
      bf16x8 A0 = *(const bf16x8*)&Abuf[0][R][blk];
      bf16x8 A1 = *(const bf16x8*)&Abuf[1][R][blk];
#pragma unroll
      for (int t=0;t<8;++t){
        bf16x8 B = as_bf(W2f[(s*8+t)*64 + lane]);
        acc2[0][t] = __builtin_amdgcn_mfma_f32_16x16x32_bf16(A0,B,acc2[0][t],0,0,0);
        acc2[1][t] = __builtin_amdgcn_mfma_f32_16x16x32_bf16(A1,B,acc2[1][t],0,0,0);
      }
    }
    __syncthreads();   // all Abuf reads done before overwrite

    // ---- h2/g2 (fwd rows live in lanes with g4 even, reg 0)
    if ((g4&1)==0){
#pragma unroll
      for (int mt=0;mt<2;++mt){
        const int em = 2*mt + (g4>>1);
#pragma unroll
        for (int t=0;t<8;++t){
          const int col = 16*t+c;
          float h2 = tanh_f(acc2[mt][t][0] + b2s[col]);
          hg2[em][col] = make_float2(h2, 1.f-h2*h2);
        }
      }
    }
    __syncthreads();

    // ---- build A' (h2 fwd row, g2*z2dot tangent rows), same swizzled layout
#pragma unroll
    for (int mt=0;mt<2;++mt){
      const int em = 2*mt + (g4>>1);
#pragma unroll
      for (int t=0;t<8;++t){
        const int col = 16*t+c;
        const float2 hg = hg2[em][col];
        const int cb = col>>3, co = col&7;
#pragma unroll
        for (int reg=0;reg<4;++reg){
          const int Rr = 4*g4+reg;
          const int key = Rr&7;
          float v = hg.y*acc2[mt][t][reg];
          if (key==0) v = hg.x;
          Abuf[mt][Rr][8*(cb^key) + co] = f2b(v);
        }
      }
    }
    __syncthreads();

    // ---- layer 3 MFMA: [32 x 128] @ [128 x 32(pad of 28)]
    f32x4 acc3[2][2];
#pragma unroll
    for (int a=0;a<2;++a){ acc3[a][0]=f32x4{0.f,0.f,0.f,0.f}; acc3[a][1]=f32x4{0.f,0.f,0.f,0.f}; }
#pragma unroll
    for (int s=0;s<4;++s){
      const int blk = 8*((4*s+g4)^r7);
      bf16x8 A0 = *(const bf16x8*)&Abuf[0][R][blk];
      bf16x8 A1 = *(const bf16x8*)&Abuf[1][R][blk];
#pragma unroll
      for (int nt=0;nt<2;++nt){
        bf16x8 B = as_bf(W3f[(s*2+nt)*64 + lane]);
        acc3[0][nt] = __builtin_amdgcn_mfma_f32_16x16x32_bf16(A0,B,acc3[0][nt],0,0,0);
        acc3[1][nt] = __builtin_amdgcn_mfma_f32_16x16x32_bf16(A1,B,acc3[1][nt],0,0,0);
      }
    }

    // ---- gradV partials (VALU): element g4, slot c<14: i=c%7, half=c/7
    if (c < 14){
      const int iv = (c<7)? c : c-7;
      const int nb = (c<7)? 0 : 64;
      float gp = 0.f;
#pragma unroll 8
      for (int nn=0; nn<64; ++nn)
        gp = fmaf(pW1s[iv][nb+nn], sbf[g4][nb+nn], gp);
      gvp2[g4][c] = gp;
    }

    // ---- scatter raw to LDS
#pragma unroll
    for (int mt=0;mt<2;++mt){
      const int em = 2*mt + (g4>>1);
      const int rb = (g4&1)*4;
#pragma unroll
      for (int nt=0;nt<2;++nt){
        const int t = 16*nt+c;
        if (t < CHOL){
#pragma unroll
          for (int reg=0;reg<4;++reg) rawb[em][rb+reg][t] = acc3[mt][nt][reg];
        }
      }
    }
    __syncthreads();

    // ---- tail: element em = g4, 16 lanes each
    float dqv[DIM];
    {
      const float* dqp = dq + (long)(ebase+g4)*DIM;
#pragma unroll
      for (int j=0;j<DIM;++j) dqv[j]=dqp[j];
    }
#pragma unroll
    for (int h=0;h<2;++h){
      const int t = c + 16*h;
      if (t < CHOL){
        const float e0 = rawb[g4][0][t] + b3s[t];
        const bool dg = (t==0)|(t==2)|(t==5)|(t==9)|(t==14)|(t==20)|(t==27);
        const float Lv = dg ? sp_f(e0) : e0;
        const float df = dg ? sig_f(e0) : 1.f;
        float s_=0.f;
#pragma unroll
        for (int j=0;j<DIM;++j) s_=fmaf(dqv[j], rawb[g4][1+j][t], s_);
        Lbs[g4][t]=Lv; dfs[g4][t]=df; dLss[g4][t]=df*s_;
      }
    }
    __syncthreads();
    if (c < DIM){
      const float* ddqp = ddq + (long)(ebase+g4)*DIM;
      float wv=0.f, uv=0.f, vv=0.f;
#pragma unroll
      for (int r=0;r<DIM;++r){
        if (r>=c){
          const int id=r*(r+1)/2+c;
          const float Lrc = Lbs[g4][id];
          wv=fmaf(Lrc,dqv[r],wv);
          uv=fmaf(Lrc,ddqp[r],uv);
          vv=fmaf(dLss[g4][id],dqv[r],vv);
        }
      }
      wbs[g4][c]=wv; ubs[g4][c]=uv; vss[g4][c]=vv;
    }
    __syncthreads();
    if (c < DIM){
      const int i=c;
      float t12=0.f;
#pragma unroll
      for (int c2=0;c2<DIM;++c2){
        if (c2<=i){
          const int id=i*(i+1)/2+c2;
          t12=fmaf(Lbs[g4][id], ubs[g4][c2]+vss[g4][c2], t12);
          t12=fmaf(dLss[g4][id], wbs[g4][c2], t12);
        }
      }
      const int TRt[CHOL]={0,1,1,2,2,2,3,3,3,3,4,4,4,4,4,5,5,5,5,5,5,6,6,6,6,6,6,6};
      const int TCt[CHOL]={0,0,1,0,1,2,0,1,2,3,0,1,2,3,4,0,1,2,3,4,5,0,1,2,3,4,5,6};
      float t3=0.f;
#pragma unroll
      for (int t=0;t<CHOL;++t)
        t3=fmaf(rawb[g4][1+i][t]*dfs[g4][t], dqv[TRt[t]]*wbs[g4][TCt[t]], t3);
      out[(long)(ebase+g4)*DIM + i] = t12 - t3 + gvp2[g4][i] + gvp2[g4][7+i];
    }
    __syncthreads();
  }
}

// ---------------- Kernel B: damping (unchanged, passed in round 1) ----------------
__global__ __launch_bounds__(256, 4) void kernB(
    const float* __restrict__ q, const float* __restrict__ dq,
    const float* __restrict__ dW1, const float* __restrict__ db1,
    const float* __restrict__ dW2, const float* __restrict__ db2,
    const float* __restrict__ dW3, const float* __restrict__ db3,
    float* __restrict__ out)
{
  __shared__ float b1s[HID], b2s[HID], b3s[CHOL];
  __shared__ float A1[4][4][HID];
  __shared__ float rawD[4][4][CHOL];
  __shared__ float LbD[4][4][CHOL];
  __shared__ float wdb[4][4][DIM];

  const int tid = threadIdx.x, w = tid >> 6, lane = tid & 63;
  for (int i = tid; i < HID; i += 256) { b1s[i] = db1[i]; b2s[i] = db2[i]; }
  if (tid < CHOL) b3s[tid] = db3[tid];
  __syncthreads();

  const int n0 = lane, n1 = lane + 64;
  const int e3 = lane >> 4;
  const int s3 = lane & 15;

  for (int it = 0; it < ITERS_B; ++it) {
    const int ebase = (it * NBLK_B + (int)blockIdx.x) * 16 + w * 4;

#pragma unroll
    for (int e = 0; e < 4; ++e) {
      const long b7 = (long)(ebase + e) * DIM;
      float xv[2*DIM];
#pragma unroll
      for (int j = 0; j < DIM; ++j) { xv[j] = q[b7+j]; xv[DIM+j] = dq[b7+j]; }
#pragma unroll
      for (int half = 0; half < 2; ++half) {
        const int n = lane + 64 * half;
        float z1 = b1s[n];
#pragma unroll
        for (int j = 0; j < 2*DIM; ++j) z1 = fmaf(xv[j], dW1[j*HID + n], z1);
        A1[w][e][n] = tanh_f(z1);
      }
    }
    __syncthreads();

    float acc[4][2];
#pragma unroll
    for (int e = 0; e < 4; ++e) { acc[e][0] = 0.f; acc[e][1] = 0.f; }
#pragma unroll 4
    for (int m = 0; m < HID; ++m) {
      const float wa = dW2[m*HID + n0], wb2 = dW2[m*HID + n1];
#pragma unroll
      for (int e = 0; e < 4; ++e) {
        const float av = A1[w][e][m];
        acc[e][0] = fmaf(av, wa, acc[e][0]);
        acc[e][1] = fmaf(av, wb2, acc[e][1]);
      }
    }
    __syncthreads();

#pragma unroll
    for (int e = 0; e < 4; ++e) {
#pragma unroll
      for (int half = 0; half < 2; ++half) {
        const int n = lane + 64 * half;
        A1[w][e][n] = tanh_f(acc[e][half] + b2s[n]);
      }
    }
    __syncthreads();

    {
      float r0 = 0.f, r1 = 0.f;
      const bool two = (s3 < 12);
#pragma unroll 4
      for (int m = 0; m < HID; ++m) {
        const float bv = A1[w][e3][m];
        r0 = fmaf(bv, dW3[m*CHOL + s3], r0);
        if (two) r1 = fmaf(bv, dW3[m*CHOL + s3 + 16], r1);
      }
      rawD[w][e3][s3] = r0 + b3s[s3];
      if (two) rawD[w][e3][s3+16] = r1 + b3s[s3+16];
    }
    __syncthreads();

#pragma unroll
    for (int k = 0; k < 2; ++k) {
      const int t = s3 + 16*k;
      if (t < CHOL) {
        const float e0 = rawD[w][e3][t];
        const bool dg = (t==0)|(t==2)|(t==5)|(t==9)|(t==14)|(t==20)|(t==27);
        LbD[w][e3][t] = dg ? sp_f(e0) : e0;
      }
    }
    __syncthreads();

    if (s3 < DIM) {
      const long b7 = (long)(ebase + e3) * DIM;
      const int cc = s3;
      float wv = 0.f;
#pragma unroll
      for (int r = 0; r < DIM; ++r) {
        if (r >= cc) wv = fmaf(LbD[w][e3][r*(r+1)/2 + cc], dq[b7 + r], wv);
      }
      wdb[w][e3][cc] = wv;
    }
    __syncthreads();

    if (s3 < DIM) {
      const long b7 = (long)(ebase + e3) * DIM;
      const int i = s3;
      float td = 0.f;
#pragma unroll
      for (int cc = 0; cc < DIM; ++cc) {
        if (cc <= i) td = fmaf(LbD[w][e3][i*(i+1)/2 + cc], wdb[w][e3][cc], td);
      }
      out[b7 + i] += td;
    }
    __syncthreads();
  }
}

extern "C" void kernel_launch(void* const* d_in, const int* in_sizes, int n_in,
                              void* d_out, int out_size, void* d_ws, size_t ws_size,
                              hipStream_t stream) {
  const float* q   = (const float*)d_in[0];
  const float* dq  = (const float*)d_in[1];
  const float* ddq = (const float*)d_in[2];
  const float* mW1 = (const float*)d_in[3];
  const float* mb1 = (const float*)d_in[4];
  const float* mW2 = (const float*)d_in[5];
  const float* mb2 = (const float*)d_in[6];
  const float* mW3 = (const float*)d_in[7];
  const float* mb3 = (const float*)d_in[8];
  const float* dW1 = (const float*)d_in[9];
  const float* db1 = (const float*)d_in[10];
  const float* dW2 = (const float*)d_in[11];
  const float* db2 = (const float*)d_in[12];
  const float* dW3 = (const float*)d_in[13];
  const float* db3 = (const float*)d_in[14];
  const float* pW1 = (const float*)d_in[15];
  const float* pb1 = (const float*)d_in[16];
  const float* pw2 = (const float*)d_in[17];
  float* out = (float*)d_out;
  unsigned* wsu = (unsigned*)d_ws;

  hipLaunchKernelGGL(setup_frags, dim3(40), dim3(256), 0, stream, mW2, mW3, wsu);
  hipLaunchKernelGGL(kernA, dim3(GRID_A), dim3(64), 0, stream,
                     q, dq, ddq, mW1, mb1, mb2, mb3, pW1, pb1, pw2, (const unsigned*)wsu, out);
  hipLaunchKernelGGL(kernB, dim3(NBLK_B), dim3(256), 0, stream,
                     q, dq, dW1, db1, dW2, db2, dW3, db3, out);
}

// Round 7
// 816.991 us; speedup vs baseline: 1.7408x; 1.0101x over previous
//
#include <hip/hip_runtime.h>

#define DIM 7
#define HID 128
#define CHOL 28

#define GRID_A 2048
#define ITER_A 16          // 2048 blocks * 4 elem * 16 iter = 131072
#define NBLK_B 1024
#define ITERS_B 8

// sched_barrier mask: ALU|VALU|SALU|MFMA|VMEM|VMEM_READ|VMEM_WRITE may cross; DS/DS_READ/DS_WRITE blocked.
#define PHASE_FENCE() __builtin_amdgcn_sched_barrier(0x7F)

typedef float    f32x4  __attribute__((ext_vector_type(4)));
typedef short    bf16x8 __attribute__((ext_vector_type(8)));
typedef unsigned uint4v __attribute__((ext_vector_type(4)));

__device__ __forceinline__ float tanh_f(float x){ float e=__expf(2.f*x); return 1.f - 2.f/(e+1.f); }
__device__ __forceinline__ float sig_f(float x){ return 1.f/(1.f+__expf(-x)); }
__device__ __forceinline__ float sp_f(float x){ return fmaxf(x,0.f) + __logf(1.f+__expf(-fabsf(x))); }

__device__ __forceinline__ unsigned short f2b(float v){
  unsigned u = __float_as_uint(v);
  u += 0x7FFFu + ((u>>16)&1u);          // RNE to bf16
  return (unsigned short)(u>>16);
}
__device__ __forceinline__ bf16x8 as_bf(uint4v u){ union { uint4v a; bf16x8 f; } x; x.a=u; return x.f; }

// ---- ws layout (u32): [0,8192) W2frag ; [8192,10240) W3frag
// frag order: u32 idx = (frag_id*64 + lane)*4 + i2 ; B[k][col], k = 32s+8*(l>>4)+2*i2(+1), col = 16t+(l&15)
// (A-frags use the SAME (group,elem)->k map, so layer-2/3 are correct for any HW intra-lane k order.)
__global__ void setup_frags(const float* __restrict__ mW2, const float* __restrict__ mW3,
                            unsigned* __restrict__ ws){
  int idx = blockIdx.x*256 + threadIdx.x;
  if (idx < 8192) {
    int i2 = idx&3, f = idx>>2, l = f&63, st = f>>6;
    int s = st>>3, t = st&7;
    int k = 32*s + 8*(l>>4) + 2*i2, col = 16*t + (l&15);
    unsigned short lo = f2b(mW2[k*HID+col]), hi = f2b(mW2[(k+1)*HID+col]);
    ws[idx] = (unsigned)lo | ((unsigned)hi<<16);
  } else if (idx < 10240) {
    int j = idx-8192; int i2=j&3, f=j>>2, l=f&63, st=f>>6;
    int s = st>>1, t = st&1;
    int k = 32*s + 8*(l>>4) + 2*i2, col = 16*t + (l&15);
    float v0 = (col<CHOL) ? mW3[k*CHOL+col] : 0.f;
    float v1 = (col<CHOL) ? mW3[(k+1)*CHOL+col] : 0.f;
    ws[idx] = (unsigned)f2b(v0) | ((unsigned)f2b(v1)<<16);
  }
}

// ---------------- Kernel A: MFMA version ----------------
// 1 wave/block, 4 elements/iter. Two 16x128 A tiles: rows 8e..8e+7 = [fwd, tan0..6] of element e.
// Abuf layout: [mt][row][k] bf16, with 16B-block XOR swizzle: k-block kb stored at kb ^ (row&7).
// Single-wave block: no __syncthreads in the loop; PHASE_FENCE() pins DS ordering at phase
// boundaries while letting global loads / MFMA / VALU flow across (no vmcnt drains).
__global__ __launch_bounds__(64, 2) void kernA(
    const float* __restrict__ q, const float* __restrict__ dq, const float* __restrict__ ddq,
    const float* __restrict__ mW1, const float* __restrict__ mb1,
    const float* __restrict__ mb2, const float* __restrict__ mb3,
    const float* __restrict__ pW1, const float* __restrict__ pb1, const float* __restrict__ pw2,
    const unsigned* __restrict__ ws, float* __restrict__ out)
{
  __shared__ __align__(16) unsigned short Abuf[2][16][HID];  // 8KB, reused for A'
  __shared__ float sbf[4][HID+8];                            // sigmoid(zp)*softplus(pw2), padded
  __shared__ float pW1s[DIM][HID+8];                         // pW1 staged, padded
  __shared__ float2 hg2[4][HID];                             // {h2, g2} per [elem][col]
  __shared__ float rawb[4][8][CHOL];
  __shared__ float b2s[HID];
  __shared__ float b3s[CHOL];
  __shared__ float Lbs[4][CHOL], dLss[4][CHOL], dfs[4][CHOL];
  __shared__ float gvp2[4][14];
  __shared__ float wbs[4][DIM], ubs[4][DIM], vss[4][DIM];

  const int lane = threadIdx.x;
  const int g4 = lane>>4, c = lane&15;
  const int R = lane&15, r7 = lane&7;

  b2s[lane] = mb2[lane]; b2s[lane+64] = mb2[lane+64];
  if (lane < CHOL) b3s[lane] = mb3[lane];
  for (int idx = lane; idx < DIM*HID; idx += 64) pW1s[idx>>7][idx&127] = pW1[idx];

  // iteration-invariant weights in registers
  float w1v0[DIM], w1v1[DIM], pw1v0[DIM], pw1v1[DIM];
#pragma unroll
  for (int j=0;j<DIM;++j){
    w1v0[j]=mW1[j*HID+lane];  w1v1[j]=mW1[j*HID+lane+64];
    pw1v0[j]=pW1[j*HID+lane]; pw1v1[j]=pW1[j*HID+lane+64];
  }
  const float b1v0=mb1[lane], b1v1=mb1[lane+64];
  const float pbv0=pb1[lane], pbv1=pb1[lane+64];
  const float sp0=sp_f(pw2[lane]), sp1=sp_f(pw2[lane+64]);

  const uint4v* __restrict__ W2f = (const uint4v*)ws;
  const uint4v* __restrict__ W3f = (const uint4v*)(ws + 8192);

  __syncthreads();   // prologue only (staged pW1s/b2s/b3s)

  for (int it=0; it<ITER_A; ++it){
    const int ebase = (it*GRID_A + (int)blockIdx.x)*4;

    // ---- phase 1: layer 1 + tangent seeds + sb
    const int kb0 = lane>>3, ko = lane&7;
#pragma unroll
    for (int e=0;e<4;++e){
      const float* qp = q + (long)(ebase+e)*DIM;
      float qv[DIM];
#pragma unroll
      for (int j=0;j<DIM;++j) qv[j]=qp[j];
      const int mt = e>>1, R0 = 8*(e&1);
      {
        float z1=b1v0, zp=pbv0;
#pragma unroll
        for (int j=0;j<DIM;++j){ z1=fmaf(qv[j],w1v0[j],z1); zp=fmaf(qv[j],pw1v0[j],zp); }
        float h1=tanh_f(z1), g1=1.f-h1*h1;
        Abuf[mt][R0][8*kb0 + ko] = f2b(h1);                      // row&7==0: kb^0
#pragma unroll
        for (int j=0;j<DIM;++j)
          Abuf[mt][R0+1+j][8*(kb0^(1+j)) + ko] = f2b(g1*w1v0[j]);
        sbf[e][lane] = sig_f(zp)*sp0;
      }
      {
        float z1=b1v1, zp=pbv1;
#pragma unroll
        for (int j=0;j<DIM;++j){ z1=fmaf(qv[j],w1v1[j],z1); zp=fmaf(qv[j],pw1v1[j],zp); }
        float h1=tanh_f(z1), g1=1.f-h1*h1;
        const int kb1 = kb0+8;
        Abuf[mt][R0][8*kb1 + ko] = f2b(h1);
#pragma unroll
        for (int j=0;j<DIM;++j)
          Abuf[mt][R0+1+j][8*(kb1^(1+j)) + ko] = f2b(g1*w1v1[j]);
        sbf[e][lane+64] = sig_f(zp)*sp1;
      }
    }
    PHASE_FENCE();   // Abuf/sbf writes before layer-2 reads

    // ---- layer 2 MFMA: [32 x 128] @ [128 x 128]
    f32x4 acc2[2][8];
#pragma unroll
    for (int a=0;a<2;++a)
#pragma unroll
      for (int b=0;b<8;++b) acc2[a][b] = f32x4{0.f,0.f,0.f,0.f};
#pragma unroll
    for (int s=0;s<4;++s){
      const int blk = 8*((4*s+g4)^r7);
      bf16x8 A0 = *(const bf16x8*)&Abuf[0][R][blk];
      bf16x8 A1 = *(const bf16x8*)&Abuf[1][R][blk];
#pragma unroll
      for (int t=0;t<8;++t){
        bf16x8 B = as_bf(W2f[(s*8+t)*64 + lane]);
        acc2[0][t] = __builtin_amdgcn_mfma_f32_16x16x32_bf16(A0,B,acc2[0][t],0,0,0);
        acc2[1][t] = __builtin_amdgcn_mfma_f32_16x16x32_bf16(A1,B,acc2[1][t],0,0,0);
      }
    }
    PHASE_FENCE();   // all Abuf reads before A' overwrite

    // ---- h2/g2 (fwd rows live in lanes with g4 even, reg 0)
    if ((g4&1)==0){
#pragma unroll
      for (int mt=0;mt<2;++mt){
        const int em = 2*mt + (g4>>1);
#pragma unroll
        for (int t=0;t<8;++t){
          const int col = 16*t+c;
          float h2 = tanh_f(acc2[mt][t][0] + b2s[col]);
          hg2[em][col] = make_float2(h2, 1.f-h2*h2);
        }
      }
    }
    PHASE_FENCE();   // hg2 writes before reads

    // ---- build A' (h2 fwd row, g2*z2dot tangent rows), same swizzled layout
#pragma unroll
    for (int mt=0;mt<2;++mt){
      const int em = 2*mt + (g4>>1);
#pragma unroll
      for (int t=0;t<8;++t){
        const int col = 16*t+c;
        const float2 hg = hg2[em][col];
        const int cb = col>>3, co = col&7;
#pragma unroll
        for (int reg=0;reg<4;++reg){
          const int Rr = 4*g4+reg;
          const int key = Rr&7;
          float v = hg.y*acc2[mt][t][reg];
          if (key==0) v = hg.x;
          Abuf[mt][Rr][8*(cb^key) + co] = f2b(v);
        }
      }
    }
    PHASE_FENCE();   // A' writes before layer-3 reads

    // ---- layer 3 MFMA: [32 x 128] @ [128 x 32(pad of 28)]
    f32x4 acc3[2][2];
#pragma unroll
    for (int a=0;a<2;++a){ acc3[a][0]=f32x4{0.f,0.f,0.f,0.f}; acc3[a][1]=f32x4{0.f,0.f,0.f,0.f}; }
#pragma unroll
    for (int s=0;s<4;++s){
      const int blk = 8*((4*s+g4)^r7);
      bf16x8 A0 = *(const bf16x8*)&Abuf[0][R][blk];
      bf16x8 A1 = *(const bf16x8*)&Abuf[1][R][blk];
#pragma unroll
      for (int nt=0;nt<2;++nt){
        bf16x8 B = as_bf(W3f[(s*2+nt)*64 + lane]);
        acc3[0][nt] = __builtin_amdgcn_mfma_f32_16x16x32_bf16(A0,B,acc3[0][nt],0,0,0);
        acc3[1][nt] = __builtin_amdgcn_mfma_f32_16x16x32_bf16(A1,B,acc3[1][nt],0,0,0);
      }
    }

    // ---- gradV partials (VALU): element g4, slot c<14: i=c%7, half=c/7
    if (c < 14){
      const int iv = (c<7)? c : c-7;
      const int nb = (c<7)? 0 : 64;
      float gp = 0.f;
#pragma unroll 8
      for (int nn=0; nn<64; ++nn)
        gp = fmaf(pW1s[iv][nb+nn], sbf[g4][nb+nn], gp);
      gvp2[g4][c] = gp;
    }

    // ---- scatter raw to LDS
#pragma unroll
    for (int mt=0;mt<2;++mt){
      const int em = 2*mt + (g4>>1);
      const int rb = (g4&1)*4;
#pragma unroll
      for (int nt=0;nt<2;++nt){
        const int t = 16*nt+c;
        if (t < CHOL){
#pragma unroll
          for (int reg=0;reg<4;++reg) rawb[em][rb+reg][t] = acc3[mt][nt][reg];
        }
      }
    }
    PHASE_FENCE();   // rawb/gvp2 writes before tail reads

    // ---- tail: element em = g4, 16 lanes each
    float dqv[DIM];
    {
      const float* dqp = dq + (long)(ebase+g4)*DIM;
#pragma unroll
      for (int j=0;j<DIM;++j) dqv[j]=dqp[j];
    }
#pragma unroll
    for (int h=0;h<2;++h){
      const int t = c + 16*h;
      if (t < CHOL){
        const float e0 = rawb[g4][0][t] + b3s[t];
        const bool dg = (t==0)|(t==2)|(t==5)|(t==9)|(t==14)|(t==20)|(t==27);
        const float Lv = dg ? sp_f(e0) : e0;
        const float df = dg ? sig_f(e0) : 1.f;
        float s_=0.f;
#pragma unroll
        for (int j=0;j<DIM;++j) s_=fmaf(dqv[j], rawb[g4][1+j][t], s_);
        Lbs[g4][t]=Lv; dfs[g4][t]=df; dLss[g4][t]=df*s_;
      }
    }
    PHASE_FENCE();   // Lbs/dfs/dLss writes before reads
    if (c < DIM){
      const float* ddqp = ddq + (long)(ebase+g4)*DIM;
      float wv=0.f, uv=0.f, vv=0.f;
#pragma unroll
      for (int r=0;r<DIM;++r){
        if (r>=c){
          const int id=r*(r+1)/2+c;
          const float Lrc = Lbs[g4][id];
          wv=fmaf(Lrc,dqv[r],wv);
          uv=fmaf(Lrc,ddqp[r],uv);
          vv=fmaf(dLss[g4][id],dqv[r],vv);
        }
      }
      wbs[g4][c]=wv; ubs[g4][c]=uv; vss[g4][c]=vv;
    }
    PHASE_FENCE();   // wbs/ubs/vss writes before reads
    if (c < DIM){
      const int i=c;
      float t12=0.f;
#pragma unroll
      for (int c2=0;c2<DIM;++c2){
        if (c2<=i){
          const int id=i*(i+1)/2+c2;
          t12=fmaf(Lbs[g4][id], ubs[g4][c2]+vss[g4][c2], t12);
          t12=fmaf(dLss[g4][id], wbs[g4][c2], t12);
        }
      }
      const int TRt[CHOL]={0,1,1,2,2,2,3,3,3,3,4,4,4,4,4,5,5,5,5,5,5,6,6,6,6,6,6,6};
      const int TCt[CHOL]={0,0,1,0,1,2,0,1,2,3,0,1,2,3,4,0,1,2,3,4,5,0,1,2,3,4,5,6};
      float t3=0.f;
#pragma unroll
      for (int t=0;t<CHOL;++t)
        t3=fmaf(rawb[g4][1+i][t]*dfs[g4][t], dqv[TRt[t]]*wbs[g4][TCt[t]], t3);
      out[(long)(ebase+g4)*DIM + i] = t12 - t3 + gvp2[g4][i] + gvp2[g4][7+i];
    }
    PHASE_FENCE();   // iteration boundary: tail reads before next phase-1 overwrites
  }
}

// ---------------- Kernel B: damping ----------------
// 4 waves/block but all LDS is [w]-indexed (per-wave): in-loop __syncthreads replaced by
// PHASE_FENCE (compile-time DS ordering only; no cross-wave sync needed, no vmcnt drains).
__global__ __launch_bounds__(256, 4) void kernB(
    const float* __restrict__ q, const float* __restrict__ dq,
    const float* __restrict__ dW1, const float* __restrict__ db1,
    const float* __restrict__ dW2, const float* __restrict__ db2,
    const float* __restrict__ dW3, const float* __restrict__ db3,
    float* __restrict__ out)
{
  __shared__ float b1s[HID], b2s[HID], b3s[CHOL];
  __shared__ float A1[4][4][HID];
  __shared__ float rawD[4][4][CHOL];
  __shared__ float LbD[4][4][CHOL];
  __shared__ float wdb[4][4][DIM];

  const int tid = threadIdx.x, w = tid >> 6, lane = tid & 63;
  for (int i = tid; i < HID; i += 256) { b1s[i] = db1[i]; b2s[i] = db2[i]; }
  if (tid < CHOL) b3s[tid] = db3[tid];
  __syncthreads();   // prologue only (b1s/b2s/b3s are cross-wave)

  const int n0 = lane, n1 = lane + 64;
  const int e3 = lane >> 4;
  const int s3 = lane & 15;

  for (int it = 0; it < ITERS_B; ++it) {
    const int ebase = (it * NBLK_B + (int)blockIdx.x) * 16 + w * 4;

#pragma unroll
    for (int e = 0; e < 4; ++e) {
      const long b7 = (long)(ebase + e) * DIM;
      float xv[2*DIM];
#pragma unroll
      for (int j = 0; j < DIM; ++j) { xv[j] = q[b7+j]; xv[DIM+j] = dq[b7+j]; }
#pragma unroll
      for (int half = 0; half < 2; ++half) {
        const int n = lane + 64 * half;
        float z1 = b1s[n];
#pragma unroll
        for (int j = 0; j < 2*DIM; ++j) z1 = fmaf(xv[j], dW1[j*HID + n], z1);
        A1[w][e][n] = tanh_f(z1);
      }
    }
    PHASE_FENCE();

    float acc[4][2];
#pragma unroll
    for (int e = 0; e < 4; ++e) { acc[e][0] = 0.f; acc[e][1] = 0.f; }
#pragma unroll 4
    for (int m = 0; m < HID; ++m) {
      const float wa = dW2[m*HID + n0], wb2 = dW2[m*HID + n1];
#pragma unroll
      for (int e = 0; e < 4; ++e) {
        const float av = A1[w][e][m];
        acc[e][0] = fmaf(av, wa, acc[e][0]);
        acc[e][1] = fmaf(av, wb2, acc[e][1]);
      }
    }
    PHASE_FENCE();

#pragma unroll
    for (int e = 0; e < 4; ++e) {
#pragma unroll
      for (int half = 0; half < 2; ++half) {
        const int n = lane + 64 * half;
        A1[w][e][n] = tanh_f(acc[e][half] + b2s[n]);
      }
    }
    PHASE_FENCE();

    {
      float r0 = 0.f, r1 = 0.f;
      const bool two = (s3 < 12);
#pragma unroll 4
      for (int m = 0; m < HID; ++m) {
        const float bv = A1[w][e3][m];
        r0 = fmaf(bv, dW3[m*CHOL + s3], r0);
        if (two) r1 = fmaf(bv, dW3[m*CHOL + s3 + 16], r1);
      }
      rawD[w][e3][s3] = r0 + b3s[s3];
      if (two) rawD[w][e3][s3+16] = r1 + b3s[s3+16];
    }
    PHASE_FENCE();

#pragma unroll
    for (int k = 0; k < 2; ++k) {
      const int t = s3 + 16*k;
      if (t < CHOL) {
        const float e0 = rawD[w][e3][t];
        const bool dg = (t==0)|(t==2)|(t==5)|(t==9)|(t==14)|(t==20)|(t==27);
        LbD[w][e3][t] = dg ? sp_f(e0) : e0;
      }
    }
    PHASE_FENCE();

    if (s3 < DIM) {
      const long b7 = (long)(ebase + e3) * DIM;
      const int cc = s3;
      float wv = 0.f;
#pragma unroll
      for (int r = 0; r < DIM; ++r) {
        if (r >= cc) wv = fmaf(LbD[w][e3][r*(r+1)/2 + cc], dq[b7 + r], wv);
      }
      wdb[w][e3][cc] = wv;
    }
    PHASE_FENCE();

    if (s3 < DIM) {
      const long b7 = (long)(ebase + e3) * DIM;
      const int i = s3;
      float td = 0.f;
#pragma unroll
      for (int cc = 0; cc < DIM; ++cc) {
        if (cc <= i) td = fmaf(LbD[w][e3][i*(i+1)/2 + cc], wdb[w][e3][cc], td);
      }
      out[b7 + i] += td;
    }
    PHASE_FENCE();
  }
}

extern "C" void kernel_launch(void* const* d_in, const int* in_sizes, int n_in,
                              void* d_out, int out_size, void* d_ws, size_t ws_size,
                              hipStream_t stream) {
  const float* q   = (const float*)d_in[0];
  const float* dq  = (const float*)d_in[1];
  const float* ddq = (const float*)d_in[2];
  const float* mW1 = (const float*)d_in[3];
  const float* mb1 = (const float*)d_in[4];
  const float* mW2 = (const float*)d_in[5];
  const float* mb2 = (const float*)d_in[6];
  const float* mW3 = (const float*)d_in[7];
  const float* mb3 = (const float*)d_in[8];
  const float* dW1 = (const float*)d_in[9];
  const float* db1 = (const float*)d_in[10];
  const float* dW2 = (const float*)d_in[11];
  const float* db2 = (const float*)d_in[12];
  const float* dW3 = (const float*)d_in[13];
  const float* db3 = (const float*)d_in[14];
  const float* pW1 = (const float*)d_in[15];
  const float* pb1 = (const float*)d_in[16];
  const float* pw2 = (const float*)d_in[17];
  float* out = (float*)d_out;
  unsigned* wsu = (unsigned*)d_ws;

  hipLaunchKernelGGL(setup_frags, dim3(40), dim3(256), 0, stream, mW2, mW3, wsu);
  hipLaunchKernelGGL(kernA, dim3(GRID_A), dim3(64), 0, stream,
                     q, dq, ddq, mW1, mb1, mb2, mb3, pW1, pb1, pw2, (const unsigned*)wsu, out);
  hipLaunchKernelGGL(kernB, dim3(NBLK_B), dim3(256), 0, stream,
                     q, dq, dW1, db1, dW2, db2, dW3, db3, out);
}

// Round 8
// 500.128 us; speedup vs baseline: 2.8437x; 1.6336x over previous
//
#include <hip/hip_runtime.h>

#define DIM 7
#define HID 128
#define CHOL 28

#define GRID_A 2048
#define ITER_A 16          // 2048 blocks * 4 elem * 16 iter = 131072
#define NBLK_B 1024
#define ITERS_B 8

// sched_barrier mask: ALU|VALU|SALU|MFMA|VMEM may cross; DS blocked (per-wave phase ordering).
#define PHASE_FENCE() __builtin_amdgcn_sched_barrier(0x7F)

typedef float    f32x4  __attribute__((ext_vector_type(4)));
typedef short    bf16x8 __attribute__((ext_vector_type(8)));
typedef unsigned uint4v __attribute__((ext_vector_type(4)));

__device__ __forceinline__ float tanh_f(float x){ float e=__expf(2.f*x); return 1.f - 2.f/(e+1.f); }
__device__ __forceinline__ float sig_f(float x){ return 1.f/(1.f+__expf(-x)); }
__device__ __forceinline__ float sp_f(float x){ return fmaxf(x,0.f) + __logf(1.f+__expf(-fabsf(x))); }

__device__ __forceinline__ unsigned short f2b(float v){
  unsigned u = __float_as_uint(v);
  u += 0x7FFFu + ((u>>16)&1u);          // RNE to bf16
  return (unsigned short)(u>>16);
}
__device__ __forceinline__ bf16x8 as_bf(uint4v u){ union { uint4v a; bf16x8 f; } x; x.a=u; return x.f; }

// ---- ws layout (u32): [0,8192) W2frag ; [8192,10240) W3frag
// frag order: u32 idx = (frag_id*64 + lane)*4 + i2 ; B[k][col], k = 32s+8*(l>>4)+2*i2(+1), col = 16t+(l&15)
// (A-frags use the SAME (group,elem)->k map, so layer-2/3 are correct for any HW intra-lane k order.)
__global__ void setup_frags(const float* __restrict__ mW2, const float* __restrict__ mW3,
                            unsigned* __restrict__ ws){
  int idx = blockIdx.x*256 + threadIdx.x;
  if (idx < 8192) {
    int i2 = idx&3, f = idx>>2, l = f&63, st = f>>6;
    int s = st>>3, t = st&7;
    int k = 32*s + 8*(l>>4) + 2*i2, col = 16*t + (l&15);
    unsigned short lo = f2b(mW2[k*HID+col]), hi = f2b(mW2[(k+1)*HID+col]);
    ws[idx] = (unsigned)lo | ((unsigned)hi<<16);
  } else if (idx < 10240) {
    int j = idx-8192; int i2=j&3, f=j>>2, l=f&63, st=f>>6;
    int s = st>>1, t = st&1;
    int k = 32*s + 8*(l>>4) + 2*i2, col = 16*t + (l&15);
    float v0 = (col<CHOL) ? mW3[k*CHOL+col] : 0.f;
    float v1 = (col<CHOL) ? mW3[(k+1)*CHOL+col] : 0.f;
    ws[idx] = (unsigned)f2b(v0) | ((unsigned)f2b(v1)<<16);
  }
}

// ---------------- Kernel A: MFMA version, B-fragments resident in VGPRs ----------------
// 1 wave/block, 4 elements/iter. Two 16x128 A tiles: rows 8e..8e+7 = [fwd, tan0..6] of element e.
// Abuf layout: [mt][row][k] bf16, 16B-block XOR swizzle: k-block kb stored at kb ^ (row&7).
// W2/W3 fragments loaded ONCE into 160 VGPRs (loop-invariant) -> zero per-iter global traffic
// in the MFMA loops; K-loop = ds_read_b128 + MFMA(reg,reg).
__global__ __launch_bounds__(64, 1) void kernA(
    const float* __restrict__ q, const float* __restrict__ dq, const float* __restrict__ ddq,
    const float* __restrict__ mW1, const float* __restrict__ mb1,
    const float* __restrict__ mb2, const float* __restrict__ mb3,
    const float* __restrict__ pW1, const float* __restrict__ pb1, const float* __restrict__ pw2,
    const unsigned* __restrict__ ws, float* __restrict__ out)
{
  __shared__ __align__(16) unsigned short Abuf[2][16][HID];  // 8KB, reused for A'
  __shared__ float sbf[4][HID+8];                            // sigmoid(zp)*softplus(pw2), padded
  __shared__ float pW1s[DIM][HID+8];                         // pW1 staged, padded
  __shared__ float2 hg2[4][HID];                             // {h2, g2} per [elem][col]
  __shared__ float rawb[4][8][CHOL];
  __shared__ float b2s[HID];
  __shared__ float b3s[CHOL];
  __shared__ float Lbs[4][CHOL], dLss[4][CHOL], dfs[4][CHOL];
  __shared__ float gvp2[4][14];
  __shared__ float wbs[4][DIM], ubs[4][DIM], vss[4][DIM];

  const int lane = threadIdx.x;
  const int g4 = lane>>4, c = lane&15;
  const int R = lane&15, r7 = lane&7;

  b2s[lane] = mb2[lane]; b2s[lane+64] = mb2[lane+64];
  if (lane < CHOL) b3s[lane] = mb3[lane];
  for (int idx = lane; idx < DIM*HID; idx += 64) pW1s[idx>>7][idx&127] = pW1[idx];

  // iteration-invariant weights in registers
  float w1v0[DIM], w1v1[DIM], pw1v0[DIM], pw1v1[DIM];
#pragma unroll
  for (int j=0;j<DIM;++j){
    w1v0[j]=mW1[j*HID+lane];  w1v1[j]=mW1[j*HID+lane+64];
    pw1v0[j]=pW1[j*HID+lane]; pw1v1[j]=pW1[j*HID+lane+64];
  }
  const float b1v0=mb1[lane], b1v1=mb1[lane+64];
  const float pbv0=pb1[lane], pbv1=pb1[lane+64];
  const float sp0=sp_f(pw2[lane]), sp1=sp_f(pw2[lane+64]);

  // B-fragments: loop-invariant, resident in VGPRs (32+8 uint4v = 160 VGPRs)
  const uint4v* __restrict__ W2f = (const uint4v*)ws;
  const uint4v* __restrict__ W3f = (const uint4v*)(ws + 8192);
  uint4v W2r[32];
#pragma unroll
  for (int i=0;i<32;++i) W2r[i] = W2f[i*64 + lane];
  uint4v W3r[8];
#pragma unroll
  for (int i=0;i<8;++i)  W3r[i] = W3f[i*64 + lane];

  __syncthreads();   // prologue only (staged pW1s/b2s/b3s)

  for (int it=0; it<ITER_A; ++it){
    const int ebase = (it*GRID_A + (int)blockIdx.x)*4;

    // ---- phase 1: layer 1 + tangent seeds + sb
    const int kb0 = lane>>3, ko = lane&7;
#pragma unroll
    for (int e=0;e<4;++e){
      const float* qp = q + (long)(ebase+e)*DIM;
      float qv[DIM];
#pragma unroll
      for (int j=0;j<DIM;++j) qv[j]=qp[j];
      const int mt = e>>1, R0 = 8*(e&1);
      {
        float z1=b1v0, zp=pbv0;
#pragma unroll
        for (int j=0;j<DIM;++j){ z1=fmaf(qv[j],w1v0[j],z1); zp=fmaf(qv[j],pw1v0[j],zp); }
        float h1=tanh_f(z1), g1=1.f-h1*h1;
        Abuf[mt][R0][8*kb0 + ko] = f2b(h1);                      // row&7==0: kb^0
#pragma unroll
        for (int j=0;j<DIM;++j)
          Abuf[mt][R0+1+j][8*(kb0^(1+j)) + ko] = f2b(g1*w1v0[j]);
        sbf[e][lane] = sig_f(zp)*sp0;
      }
      {
        float z1=b1v1, zp=pbv1;
#pragma unroll
        for (int j=0;j<DIM;++j){ z1=fmaf(qv[j],w1v1[j],z1); zp=fmaf(qv[j],pw1v1[j],zp); }
        float h1=tanh_f(z1), g1=1.f-h1*h1;
        const int kb1 = kb0+8;
        Abuf[mt][R0][8*kb1 + ko] = f2b(h1);
#pragma unroll
        for (int j=0;j<DIM;++j)
          Abuf[mt][R0+1+j][8*(kb1^(1+j)) + ko] = f2b(g1*w1v1[j]);
        sbf[e][lane+64] = sig_f(zp)*sp1;
      }
    }
    PHASE_FENCE();   // Abuf/sbf writes before layer-2 reads

    // ---- layer 2 MFMA: [32 x 128] @ [128 x 128], B in registers
    f32x4 acc2[2][8];
#pragma unroll
    for (int a=0;a<2;++a)
#pragma unroll
      for (int b=0;b<8;++b) acc2[a][b] = f32x4{0.f,0.f,0.f,0.f};
#pragma unroll
    for (int s=0;s<4;++s){
      const int blk = 8*((4*s+g4)^r7);
      bf16x8 A0 = *(const bf16x8*)&Abuf[0][R][blk];
      bf16x8 A1 = *(const bf16x8*)&Abuf[1][R][blk];
#pragma unroll
      for (int t=0;t<8;++t){
        bf16x8 B = as_bf(W2r[s*8+t]);
        acc2[0][t] = __builtin_amdgcn_mfma_f32_16x16x32_bf16(A0,B,acc2[0][t],0,0,0);
        acc2[1][t] = __builtin_amdgcn_mfma_f32_16x16x32_bf16(A1,B,acc2[1][t],0,0,0);
      }
    }
    PHASE_FENCE();   // all Abuf reads before A' overwrite

    // ---- h2/g2 (fwd rows live in lanes with g4 even, reg 0)
    if ((g4&1)==0){
#pragma unroll
      for (int mt=0;mt<2;++mt){
        const int em = 2*mt + (g4>>1);
#pragma unroll
        for (int t=0;t<8;++t){
          const int col = 16*t+c;
          float h2 = tanh_f(acc2[mt][t][0] + b2s[col]);
          hg2[em][col] = make_float2(h2, 1.f-h2*h2);
        }
      }
    }
    PHASE_FENCE();   // hg2 writes before reads

    // ---- build A' (h2 fwd row, g2*z2dot tangent rows), same swizzled layout
#pragma unroll
    for (int mt=0;mt<2;++mt){
      const int em = 2*mt + (g4>>1);
#pragma unroll
      for (int t=0;t<8;++t){
        const int col = 16*t+c;
        const float2 hg = hg2[em][col];
        const int cb = col>>3, co = col&7;
#pragma unroll
        for (int reg=0;reg<4;++reg){
          const int Rr = 4*g4+reg;
          const int key = Rr&7;
          float v = hg.y*acc2[mt][t][reg];
          if (key==0) v = hg.x;
          Abuf[mt][Rr][8*(cb^key) + co] = f2b(v);
        }
      }
    }
    PHASE_FENCE();   // A' writes before layer-3 reads

    // ---- layer 3 MFMA: [32 x 128] @ [128 x 32(pad of 28)], B in registers
    f32x4 acc3[2][2];
#pragma unroll
    for (int a=0;a<2;++a){ acc3[a][0]=f32x4{0.f,0.f,0.f,0.f}; acc3[a][1]=f32x4{0.f,0.f,0.f,0.f}; }
#pragma unroll
    for (int s=0;s<4;++s){
      const int blk = 8*((4*s+g4)^r7);
      bf16x8 A0 = *(const bf16x8*)&Abuf[0][R][blk];
      bf16x8 A1 = *(const bf16x8*)&Abuf[1][R][blk];
#pragma unroll
      for (int nt=0;nt<2;++nt){
        bf16x8 B = as_bf(W3r[s*2+nt]);
        acc3[0][nt] = __builtin_amdgcn_mfma_f32_16x16x32_bf16(A0,B,acc3[0][nt],0,0,0);
        acc3[1][nt] = __builtin_amdgcn_mfma_f32_16x16x32_bf16(A1,B,acc3[1][nt],0,0,0);
      }
    }

    // ---- gradV partials (VALU): element g4, slot c<14: i=c%7, half=c/7
    if (c < 14){
      const int iv = (c<7)? c : c-7;
      const int nb = (c<7)? 0 : 64;
      float gp = 0.f;
#pragma unroll 8
      for (int nn=0; nn<64; ++nn)
        gp = fmaf(pW1s[iv][nb+nn], sbf[g4][nb+nn], gp);
      gvp2[g4][c] = gp;
    }

    // ---- scatter raw to LDS
#pragma unroll
    for (int mt=0;mt<2;++mt){
      const int em = 2*mt + (g4>>1);
      const int rb = (g4&1)*4;
#pragma unroll
      for (int nt=0;nt<2;++nt){
        const int t = 16*nt+c;
        if (t < CHOL){
#pragma unroll
          for (int reg=0;reg<4;++reg) rawb[em][rb+reg][t] = acc3[mt][nt][reg];
        }
      }
    }
    PHASE_FENCE();   // rawb/gvp2 writes before tail reads

    // ---- tail: element em = g4, 16 lanes each
    float dqv[DIM];
    {
      const float* dqp = dq + (long)(ebase+g4)*DIM;
#pragma unroll
      for (int j=0;j<DIM;++j) dqv[j]=dqp[j];
    }
#pragma unroll
    for (int h=0;h<2;++h){
      const int t = c + 16*h;
      if (t < CHOL){
        const float e0 = rawb[g4][0][t] + b3s[t];
        const bool dg = (t==0)|(t==2)|(t==5)|(t==9)|(t==14)|(t==20)|(t==27);
        const float Lv = dg ? sp_f(e0) : e0;
        const float df = dg ? sig_f(e0) : 1.f;
        float s_=0.f;
#pragma unroll
        for (int j=0;j<DIM;++j) s_=fmaf(dqv[j], rawb[g4][1+j][t], s_);
        Lbs[g4][t]=Lv; dfs[g4][t]=df; dLss[g4][t]=df*s_;
      }
    }
    PHASE_FENCE();   // Lbs/dfs/dLss writes before reads
    if (c < DIM){
      const float* ddqp = ddq + (long)(ebase+g4)*DIM;
      float wv=0.f, uv=0.f, vv=0.f;
#pragma unroll
      for (int r=0;r<DIM;++r){
        if (r>=c){
          const int id=r*(r+1)/2+c;
          const float Lrc = Lbs[g4][id];
          wv=fmaf(Lrc,dqv[r],wv);
          uv=fmaf(Lrc,ddqp[r],uv);
          vv=fmaf(dLss[g4][id],dqv[r],vv);
        }
      }
      wbs[g4][c]=wv; ubs[g4][c]=uv; vss[g4][c]=vv;
    }
    PHASE_FENCE();   // wbs/ubs/vss writes before reads
    if (c < DIM){
      const int i=c;
      float t12=0.f;
#pragma unroll
      for (int c2=0;c2<DIM;++c2){
        if (c2<=i){
          const int id=i*(i+1)/2+c2;
          t12=fmaf(Lbs[g4][id], ubs[g4][c2]+vss[g4][c2], t12);
          t12=fmaf(dLss[g4][id], wbs[g4][c2], t12);
        }
      }
      const int TRt[CHOL]={0,1,1,2,2,2,3,3,3,3,4,4,4,4,4,5,5,5,5,5,5,6,6,6,6,6,6,6};
      const int TCt[CHOL]={0,0,1,0,1,2,0,1,2,3,0,1,2,3,4,0,1,2,3,4,5,0,1,2,3,4,5,6};
      float t3=0.f;
#pragma unroll
      for (int t=0;t<CHOL;++t)
        t3=fmaf(rawb[g4][1+i][t]*dfs[g4][t], dqv[TRt[t]]*wbs[g4][TCt[t]], t3);
      out[(long)(ebase+g4)*DIM + i] = t12 - t3 + gvp2[g4][i] + gvp2[g4][7+i];
    }
    PHASE_FENCE();   // iteration boundary: tail reads before next phase-1 overwrites
  }
}

// ---------------- Kernel B: damping ----------------
// 4 waves/block, all LDS [w]-indexed (per-wave): PHASE_FENCE ordering only (no cross-wave sync).
__global__ __launch_bounds__(256, 4) void kernB(
    const float* __restrict__ q, const float* __restrict__ dq,
    const float* __restrict__ dW1, const float* __restrict__ db1,
    const float* __restrict__ dW2, const float* __restrict__ db2,
    const float* __restrict__ dW3, const float* __restrict__ db3,
    float* __restrict__ out)
{
  __shared__ float b1s[HID], b2s[HID], b3s[CHOL];
  __shared__ float A1[4][4][HID];
  __shared__ float rawD[4][4][CHOL];
  __shared__ float LbD[4][4][CHOL];
  __shared__ float wdb[4][4][DIM];

  const int tid = threadIdx.x, w = tid >> 6, lane = tid & 63;
  for (int i = tid; i < HID; i += 256) { b1s[i] = db1[i]; b2s[i] = db2[i]; }
  if (tid < CHOL) b3s[tid] = db3[tid];
  __syncthreads();   // prologue only (b1s/b2s/b3s are cross-wave)

  const int n0 = lane, n1 = lane + 64;
  const int e3 = lane >> 4;
  const int s3 = lane & 15;

  for (int it = 0; it < ITERS_B; ++it) {
    const int ebase = (it * NBLK_B + (int)blockIdx.x) * 16 + w * 4;

#pragma unroll
    for (int e = 0; e < 4; ++e) {
      const long b7 = (long)(ebase + e) * DIM;
      float xv[2*DIM];
#pragma unroll
      for (int j = 0; j < DIM; ++j) { xv[j] = q[b7+j]; xv[DIM+j] = dq[b7+j]; }
#pragma unroll
      for (int half = 0; half < 2; ++half) {
        const int n = lane + 64 * half;
        float z1 = b1s[n];
#pragma unroll
        for (int j = 0; j < 2*DIM; ++j) z1 = fmaf(xv[j], dW1[j*HID + n], z1);
        A1[w][e][n] = tanh_f(z1);
      }
    }
    PHASE_FENCE();

    float acc[4][2];
#pragma unroll
    for (int e = 0; e < 4; ++e) { acc[e][0] = 0.f; acc[e][1] = 0.f; }
#pragma unroll 4
    for (int m = 0; m < HID; ++m) {
      const float wa = dW2[m*HID + n0], wb2 = dW2[m*HID + n1];
#pragma unroll
      for (int e = 0; e < 4; ++e) {
        const float av = A1[w][e][m];
        acc[e][0] = fmaf(av, wa, acc[e][0]);
        acc[e][1] = fmaf(av, wb2, acc[e][1]);
      }
    }
    PHASE_FENCE();

#pragma unroll
    for (int e = 0; e < 4; ++e) {
#pragma unroll
      for (int half = 0; half < 2; ++half) {
        const int n = lane + 64 * half;
        A1[w][e][n] = tanh_f(acc[e][half] + b2s[n]);
      }
    }
    PHASE_FENCE();

    {
      float r0 = 0.f, r1 = 0.f;
      const bool two = (s3 < 12);
#pragma unroll 4
      for (int m = 0; m < HID; ++m) {
        const float bv = A1[w][e3][m];
        r0 = fmaf(bv, dW3[m*CHOL + s3], r0);
        if (two) r1 = fmaf(bv, dW3[m*CHOL + s3 + 16], r1);
      }
      rawD[w][e3][s3] = r0 + b3s[s3];
      if (two) rawD[w][e3][s3+16] = r1 + b3s[s3+16];
    }
    PHASE_FENCE();

#pragma unroll
    for (int k = 0; k < 2; ++k) {
      const int t = s3 + 16*k;
      if (t < CHOL) {
        const float e0 = rawD[w][e3][t];
        const bool dg = (t==0)|(t==2)|(t==5)|(t==9)|(t==14)|(t==20)|(t==27);
        LbD[w][e3][t] = dg ? sp_f(e0) : e0;
      }
    }
    PHASE_FENCE();

    if (s3 < DIM) {
      const long b7 = (long)(ebase + e3) * DIM;
      const int cc = s3;
      float wv = 0.f;
#pragma unroll
      for (int r = 0; r < DIM; ++r) {
        if (r >= cc) wv = fmaf(LbD[w][e3][r*(r+1)/2 + cc], dq[b7 + r], wv);
      }
      wdb[w][e3][cc] = wv;
    }
    PHASE_FENCE();

    if (s3 < DIM) {
      const long b7 = (long)(ebase + e3) * DIM;
      const int i = s3;
      float td = 0.f;
#pragma unroll
      for (int cc = 0; cc < DIM; ++cc) {
        if (cc <= i) td = fmaf(LbD[w][e3][i*(i+1)/2 + cc], wdb[w][e3][cc], td);
      }
      out[b7 + i] += td;
    }
    PHASE_FENCE();
  }
}

extern "C" void kernel_launch(void* const* d_in, const int* in_sizes, int n_in,
                              void* d_out, int out_size, void* d_ws, size_t ws_size,
                              hipStream_t stream) {
  const float* q   = (const float*)d_in[0];
  const float* dq  = (const float*)d_in[1];
  const float* ddq = (const float*)d_in[2];
  const float* mW1 = (const float*)d_in[3];
  const float* mb1 = (const float*)d_in[4];
  const float* mW2 = (const float*)d_in[5];
  const float* mb2 = (const float*)d_in[6];
  const float* mW3 = (const float*)d_in[7];
  const float* mb3 = (const float*)d_in[8];
  const float* dW1 = (const float*)d_in[9];
  const float* db1 = (const float*)d_in[10];
  const float* dW2 = (const float*)d_in[11];
  const float* db2 = (const float*)d_in[12];
  const float* dW3 = (const float*)d_in[13];
  const float* db3 = (const float*)d_in[14];
  const float* pW1 = (const float*)d_in[15];
  const float* pb1 = (const float*)d_in[16];
  const float* pw2 = (const float*)d_in[17];
  float* out = (float*)d_out;
  unsigned* wsu = (unsigned*)d_ws;

  hipLaunchKernelGGL(setup_frags, dim3(40), dim3(256), 0, stream, mW2, mW3, wsu);
  hipLaunchKernelGGL(kernA, dim3(GRID_A), dim3(64), 0, stream,
                     q, dq, ddq, mW1, mb1, mb2, mb3, pW1, pb1, pw2, (const unsigned*)wsu, out);
  hipLaunchKernelGGL(kernB, dim3(NBLK_B), dim3(256), 0, stream,
                     q, dq, dW1, db1, dW2, db2, dW3, db3, out);
}

// Round 9
// 371.566 us; speedup vs baseline: 3.8276x; 1.3460x over previous
//
#include <hip/hip_runtime.h>

#define DIM 7
#define HID 128
#define CHOL 28

#define GRID_A 2048
#define ITER_A 16          // 2048 blocks * 4 elem * 16 iter = 131072
#define GRID_B 2048
#define ITER_B 4           // 2048 blocks * 16 elem * 4 iter = 131072

// sched_barrier mask: ALU|VALU|SALU|MFMA|VMEM may cross; DS blocked (per-wave phase ordering).
#define PHASE_FENCE() __builtin_amdgcn_sched_barrier(0x7F)

typedef float    f32x4  __attribute__((ext_vector_type(4)));
typedef short    bf16x8 __attribute__((ext_vector_type(8)));
typedef unsigned uint4v __attribute__((ext_vector_type(4)));

__device__ __forceinline__ float tanh_f(float x){ float e=__expf(2.f*x); return 1.f - 2.f/(e+1.f); }
__device__ __forceinline__ float sig_f(float x){ return 1.f/(1.f+__expf(-x)); }
__device__ __forceinline__ float sp_f(float x){ return fmaxf(x,0.f) + __logf(1.f+__expf(-fabsf(x))); }

__device__ __forceinline__ unsigned short f2b(float v){
  unsigned u = __float_as_uint(v);
  u += 0x7FFFu + ((u>>16)&1u);          // RNE to bf16
  return (unsigned short)(u>>16);
}
__device__ __forceinline__ bf16x8 as_bf(uint4v u){ union { uint4v a; bf16x8 f; } x; x.a=u; return x.f; }

// ---- ws layout (u32): [0,8192) W2frag ; [8192,10240) W3frag ; [10240,18432) dW2frag ;
//                       [18432,20480) dW3frag   (80 KB total)
// frag order: u32 idx = (frag_id*64 + lane)*4 + i2 ; B[k][col], k = 32s+8*(l>>4)+2*i2(+1), col = 16t+(l&15)
// (A-frags use the SAME (group,elem)->k map, so layer-2/3 are correct for any HW intra-lane k order.)
__global__ void setup_frags(const float* __restrict__ mW2, const float* __restrict__ mW3,
                            const float* __restrict__ dW2, const float* __restrict__ dW3,
                            unsigned* __restrict__ ws){
  int idx = blockIdx.x*256 + threadIdx.x;
  if (idx < 8192) {
    int i2 = idx&3, f = idx>>2, l = f&63, st = f>>6;
    int s = st>>3, t = st&7;
    int k = 32*s + 8*(l>>4) + 2*i2, col = 16*t + (l&15);
    unsigned short lo = f2b(mW2[k*HID+col]), hi = f2b(mW2[(k+1)*HID+col]);
    ws[idx] = (unsigned)lo | ((unsigned)hi<<16);
  } else if (idx < 10240) {
    int j = idx-8192; int i2=j&3, f=j>>2, l=f&63, st=f>>6;
    int s = st>>1, t = st&1;
    int k = 32*s + 8*(l>>4) + 2*i2, col = 16*t + (l&15);
    float v0 = (col<CHOL) ? mW3[k*CHOL+col] : 0.f;
    float v1 = (col<CHOL) ? mW3[(k+1)*CHOL+col] : 0.f;
    ws[idx] = (unsigned)f2b(v0) | ((unsigned)f2b(v1)<<16);
  } else if (idx < 18432) {
    int j = idx-10240; int i2=j&3, f=j>>2, l=f&63, st=f>>6;
    int s = st>>3, t = st&7;
    int k = 32*s + 8*(l>>4) + 2*i2, col = 16*t + (l&15);
    unsigned short lo = f2b(dW2[k*HID+col]), hi = f2b(dW2[(k+1)*HID+col]);
    ws[idx] = (unsigned)lo | ((unsigned)hi<<16);
  } else if (idx < 20480) {
    int j = idx-18432; int i2=j&3, f=j>>2, l=f&63, st=f>>6;
    int s = st>>1, t = st&1;
    int k = 32*s + 8*(l>>4) + 2*i2, col = 16*t + (l&15);
    float v0 = (col<CHOL) ? dW3[k*CHOL+col] : 0.f;
    float v1 = (col<CHOL) ? dW3[(k+1)*CHOL+col] : 0.f;
    ws[idx] = (unsigned)f2b(v0) | ((unsigned)f2b(v1)<<16);
  }
}

// ---------------- Kernel A: MFMA, B-frags in VGPRs, h2 via shfl (no hg2 LDS) ----------------
// 1 wave/block, 4 elements/iter. Two 16x128 A tiles: rows 8e..8e+7 = [fwd, tan0..6] of element e.
// Abuf layout: [mt][row][k] bf16, 16B-block XOR swizzle: k-block kb stored at kb ^ (row&7).
// LDS = 20.0 KB -> 8 blocks/CU (2 waves/SIMD) with VGPR 224.
__global__ __launch_bounds__(64, 1) void kernA(
    const float* __restrict__ q, const float* __restrict__ dq, const float* __restrict__ ddq,
    const float* __restrict__ mW1, const float* __restrict__ mb1,
    const float* __restrict__ mb2, const float* __restrict__ mb3,
    const float* __restrict__ pW1, const float* __restrict__ pb1, const float* __restrict__ pw2,
    const unsigned* __restrict__ ws, float* __restrict__ out)
{
  __shared__ __align__(16) unsigned short Abuf[2][16][HID];  // 8KB, reused for A'
  __shared__ float sbf[4][HID+8];                            // sigmoid(zp)*softplus(pw2), padded
  __shared__ float pW1s[DIM][HID+8];                         // pW1 staged, padded
  __shared__ float rawb[4][8][CHOL];
  __shared__ float b2s[HID];
  __shared__ float b3s[CHOL];
  __shared__ float Lbs[4][CHOL], dLss[4][CHOL], dfs[4][CHOL];
  __shared__ float gvp2[4][14];
  __shared__ float wbs[4][DIM], ubs[4][DIM], vss[4][DIM];

  const int lane = threadIdx.x;
  const int g4 = lane>>4, c = lane&15;
  const int R = lane&15, r7 = lane&7;

  b2s[lane] = mb2[lane]; b2s[lane+64] = mb2[lane+64];
  if (lane < CHOL) b3s[lane] = mb3[lane];
  for (int idx = lane; idx < DIM*HID; idx += 64) pW1s[idx>>7][idx&127] = pW1[idx];

  // iteration-invariant weights in registers
  float w1v0[DIM], w1v1[DIM], pw1v0[DIM], pw1v1[DIM];
#pragma unroll
  for (int j=0;j<DIM;++j){
    w1v0[j]=mW1[j*HID+lane];  w1v1[j]=mW1[j*HID+lane+64];
    pw1v0[j]=pW1[j*HID+lane]; pw1v1[j]=pW1[j*HID+lane+64];
  }
  const float b1v0=mb1[lane], b1v1=mb1[lane+64];
  const float pbv0=pb1[lane], pbv1=pb1[lane+64];
  const float sp0=sp_f(pw2[lane]), sp1=sp_f(pw2[lane+64]);

  // B-fragments: loop-invariant, resident in VGPRs (32+8 uint4v = 160 VGPRs)
  const uint4v* __restrict__ W2f = (const uint4v*)ws;
  const uint4v* __restrict__ W3f = (const uint4v*)(ws + 8192);
  uint4v W2r[32];
#pragma unroll
  for (int i=0;i<32;++i) W2r[i] = W2f[i*64 + lane];
  uint4v W3r[8];
#pragma unroll
  for (int i=0;i<8;++i)  W3r[i] = W3f[i*64 + lane];

  __syncthreads();   // prologue only (staged pW1s/b2s/b3s)

  for (int it=0; it<ITER_A; ++it){
    const int ebase = (it*GRID_A + (int)blockIdx.x)*4;

    // ---- phase 1: layer 1 + tangent seeds + sb
    const int kb0 = lane>>3, ko = lane&7;
#pragma unroll
    for (int e=0;e<4;++e){
      const float* qp = q + (long)(ebase+e)*DIM;
      float qv[DIM];
#pragma unroll
      for (int j=0;j<DIM;++j) qv[j]=qp[j];
      const int mt = e>>1, R0 = 8*(e&1);
      {
        float z1=b1v0, zp=pbv0;
#pragma unroll
        for (int j=0;j<DIM;++j){ z1=fmaf(qv[j],w1v0[j],z1); zp=fmaf(qv[j],pw1v0[j],zp); }
        float h1=tanh_f(z1), g1=1.f-h1*h1;
        Abuf[mt][R0][8*kb0 + ko] = f2b(h1);                      // row&7==0: kb^0
#pragma unroll
        for (int j=0;j<DIM;++j)
          Abuf[mt][R0+1+j][8*(kb0^(1+j)) + ko] = f2b(g1*w1v0[j]);
        sbf[e][lane] = sig_f(zp)*sp0;
      }
      {
        float z1=b1v1, zp=pbv1;
#pragma unroll
        for (int j=0;j<DIM;++j){ z1=fmaf(qv[j],w1v1[j],z1); zp=fmaf(qv[j],pw1v1[j],zp); }
        float h1=tanh_f(z1), g1=1.f-h1*h1;
        const int kb1 = kb0+8;
        Abuf[mt][R0][8*kb1 + ko] = f2b(h1);
#pragma unroll
        for (int j=0;j<DIM;++j)
          Abuf[mt][R0+1+j][8*(kb1^(1+j)) + ko] = f2b(g1*w1v1[j]);
        sbf[e][lane+64] = sig_f(zp)*sp1;
      }
    }
    PHASE_FENCE();   // Abuf/sbf writes before layer-2 reads

    // ---- layer 2 MFMA: [32 x 128] @ [128 x 128], B in registers
    f32x4 acc2[2][8];
#pragma unroll
    for (int a=0;a<2;++a)
#pragma unroll
      for (int b=0;b<8;++b) acc2[a][b] = f32x4{0.f,0.f,0.f,0.f};
#pragma unroll
    for (int s=0;s<4;++s){
      const int blk = 8*((4*s+g4)^r7);
      bf16x8 A0 = *(const bf16x8*)&Abuf[0][R][blk];
      bf16x8 A1 = *(const bf16x8*)&Abuf[1][R][blk];
#pragma unroll
      for (int t=0;t<8;++t){
        bf16x8 B = as_bf(W2r[s*8+t]);
        acc2[0][t] = __builtin_amdgcn_mfma_f32_16x16x32_bf16(A0,B,acc2[0][t],0,0,0);
        acc2[1][t] = __builtin_amdgcn_mfma_f32_16x16x32_bf16(A1,B,acc2[1][t],0,0,0);
      }
    }
    PHASE_FENCE();   // all Abuf reads before A' overwrite

    // ---- h2 via lane-pair shuffle (even g4 owns fwd row reg0), build A' in place
#pragma unroll
    for (int mt=0;mt<2;++mt){
#pragma unroll
      for (int t=0;t<8;++t){
        const int col = 16*t+c;
        const float z2  = acc2[mt][t][0] + b2s[col];
        const float h2o = tanh_f(z2);                 // valid on even g4; finite garbage on odd
        const float h2x = __shfl_xor(h2o, 16);
        const float h2  = (g4&1) ? h2x : h2o;
        const float g2  = 1.f - h2*h2;
        const int cb = col>>3, co = col&7;
#pragma unroll
        for (int reg=0;reg<4;++reg){
          const int Rr = 4*g4+reg;
          const int key = Rr&7;
          float v = g2*acc2[mt][t][reg];
          if (key==0) v = h2;
          Abuf[mt][Rr][8*(cb^key) + co] = f2b(v);
        }
      }
    }
    PHASE_FENCE();   // A' writes before layer-3 reads

    // ---- layer 3 MFMA: [32 x 128] @ [128 x 32(pad of 28)], B in registers
    f32x4 acc3[2][2];
#pragma unroll
    for (int a=0;a<2;++a){ acc3[a][0]=f32x4{0.f,0.f,0.f,0.f}; acc3[a][1]=f32x4{0.f,0.f,0.f,0.f}; }
#pragma unroll
    for (int s=0;s<4;++s){
      const int blk = 8*((4*s+g4)^r7);
      bf16x8 A0 = *(const bf16x8*)&Abuf[0][R][blk];
      bf16x8 A1 = *(const bf16x8*)&Abuf[1][R][blk];
#pragma unroll
      for (int nt=0;nt<2;++nt){
        bf16x8 B = as_bf(W3r[s*2+nt]);
        acc3[0][nt] = __builtin_amdgcn_mfma_f32_16x16x32_bf16(A0,B,acc3[0][nt],0,0,0);
        acc3[1][nt] = __builtin_amdgcn_mfma_f32_16x16x32_bf16(A1,B,acc3[1][nt],0,0,0);
      }
    }

    // ---- gradV partials (VALU): element g4, slot c<14: i=c%7, half=c/7
    if (c < 14){
      const int iv = (c<7)? c : c-7;
      const int nb = (c<7)? 0 : 64;
      float gp = 0.f;
#pragma unroll 8
      for (int nn=0; nn<64; ++nn)
        gp = fmaf(pW1s[iv][nb+nn], sbf[g4][nb+nn], gp);
      gvp2[g4][c] = gp;
    }

    // ---- scatter raw to LDS
#pragma unroll
    for (int mt=0;mt<2;++mt){
      const int em = 2*mt + (g4>>1);
      const int rb = (g4&1)*4;
#pragma unroll
      for (int nt=0;nt<2;++nt){
        const int t = 16*nt+c;
        if (t < CHOL){
#pragma unroll
          for (int reg=0;reg<4;++reg) rawb[em][rb+reg][t] = acc3[mt][nt][reg];
        }
      }
    }
    PHASE_FENCE();   // rawb/gvp2 writes before tail reads

    // ---- tail: element em = g4, 16 lanes each
    float dqv[DIM];
    {
      const float* dqp = dq + (long)(ebase+g4)*DIM;
#pragma unroll
      for (int j=0;j<DIM;++j) dqv[j]=dqp[j];
    }
#pragma unroll
    for (int h=0;h<2;++h){
      const int t = c + 16*h;
      if (t < CHOL){
        const float e0 = rawb[g4][0][t] + b3s[t];
        const bool dg = (t==0)|(t==2)|(t==5)|(t==9)|(t==14)|(t==20)|(t==27);
        const float Lv = dg ? sp_f(e0) : e0;
        const float df = dg ? sig_f(e0) : 1.f;
        float s_=0.f;
#pragma unroll
        for (int j=0;j<DIM;++j) s_=fmaf(dqv[j], rawb[g4][1+j][t], s_);
        Lbs[g4][t]=Lv; dfs[g4][t]=df; dLss[g4][t]=df*s_;
      }
    }
    PHASE_FENCE();   // Lbs/dfs/dLss writes before reads
    if (c < DIM){
      const float* ddqp = ddq + (long)(ebase+g4)*DIM;
      float wv=0.f, uv=0.f, vv=0.f;
#pragma unroll
      for (int r=0;r<DIM;++r){
        if (r>=c){
          const int id=r*(r+1)/2+c;
          const float Lrc = Lbs[g4][id];
          wv=fmaf(Lrc,dqv[r],wv);
          uv=fmaf(Lrc,ddqp[r],uv);
          vv=fmaf(dLss[g4][id],dqv[r],vv);
        }
      }
      wbs[g4][c]=wv; ubs[g4][c]=uv; vss[g4][c]=vv;
    }
    PHASE_FENCE();   // wbs/ubs/vss writes before reads
    if (c < DIM){
      const int i=c;
      float t12=0.f;
#pragma unroll
      for (int c2=0;c2<DIM;++c2){
        if (c2<=i){
          const int id=i*(i+1)/2+c2;
          t12=fmaf(Lbs[g4][id], ubs[g4][c2]+vss[g4][c2], t12);
          t12=fmaf(dLss[g4][id], wbs[g4][c2], t12);
        }
      }
      const int TRt[CHOL]={0,1,1,2,2,2,3,3,3,3,4,4,4,4,4,5,5,5,5,5,5,6,6,6,6,6,6,6};
      const int TCt[CHOL]={0,0,1,0,1,2,0,1,2,3,0,1,2,3,4,0,1,2,3,4,5,0,1,2,3,4,5,6};
      float t3=0.f;
#pragma unroll
      for (int t=0;t<CHOL;++t)
        t3=fmaf(rawb[g4][1+i][t]*dfs[g4][t], dqv[TRt[t]]*wbs[g4][TCt[t]], t3);
      out[(long)(ebase+g4)*DIM + i] = t12 - t3 + gvp2[g4][i] + gvp2[g4][7+i];
    }
    PHASE_FENCE();   // iteration boundary: tail reads before next phase-1 overwrites
  }
}

// ---------------- Kernel B: damping, MFMA version ----------------
// 1 wave/block, 16 elements/iter = one 16x128 A tile (D-MLP has no tangent rows).
// Same swizzled Abuf staging + B-frags-in-VGPR as kernA. Tail: 4 lanes/element.
__global__ __launch_bounds__(64, 1) void kernB(
    const float* __restrict__ q, const float* __restrict__ dq,
    const float* __restrict__ dW1, const float* __restrict__ db1,
    const float* __restrict__ db2, const float* __restrict__ db3,
    const unsigned* __restrict__ ws, float* __restrict__ out)
{
  __shared__ __align__(16) unsigned short AbufD[16][HID];  // 4KB, reused for A'
  __shared__ float dW1s[2*DIM][HID];                        // 7KB (layer-1 weights)
  __shared__ float xsf[112+8], dsf[112+8];                  // q/dq rows, flat [e*7+j]
  __shared__ float rawD[16][CHOL];
  __shared__ float LbD[16][CHOL];
  __shared__ float wdb[16][8];
  __shared__ float b2sD[HID];
  __shared__ float b3sD[CHOL];

  const int lane = threadIdx.x;
  const int g4 = lane>>4, c = lane&15;
  const int R = lane&15, rkey = lane&7;
  const int eL = lane>>2, sub = lane&3;

  b2sD[lane] = db2[lane]; b2sD[lane+64] = db2[lane+64];
  if (lane < CHOL) b3sD[lane] = db3[lane];
  for (int idx = lane; idx < 2*DIM*HID; idx += 64) dW1s[idx>>7][idx&127] = dW1[idx];
  const float b1v0 = db1[lane], b1v1 = db1[lane+64];

  const uint4v* __restrict__ W2fD = (const uint4v*)(ws + 10240);
  const uint4v* __restrict__ W3fD = (const uint4v*)(ws + 18432);
  uint4v W2rD[32];
#pragma unroll
  for (int i=0;i<32;++i) W2rD[i] = W2fD[i*64 + lane];
  uint4v W3rD[8];
#pragma unroll
  for (int i=0;i<8;++i)  W3rD[i] = W3fD[i*64 + lane];

  __syncthreads();   // prologue only

  for (int it=0; it<ITER_B; ++it){
    const int ebase = (it*GRID_B + (int)blockIdx.x)*16;

    // ---- stage x = [q,dq] rows (16 elements x 7)
    for (int idx=lane; idx<112; idx+=64){
      xsf[idx] = q[(long)ebase*DIM + idx];
      dsf[idx] = dq[(long)ebase*DIM + idx];
    }
    PHASE_FENCE();

    // ---- layer 1: z = [q,dq] @ dW1 + b1 ; stage h1 into swizzled Abuf
#pragma unroll
    for (int h=0; h<2; ++h){
      const int k = lane + 64*h;
      float z[16];
#pragma unroll
      for (int e=0;e<16;++e) z[e] = h ? b1v1 : b1v0;
#pragma unroll
      for (int j=0;j<DIM;++j){
        const float dj = dW1s[j][k & 127];
#pragma unroll
        for (int e=0;e<16;++e) z[e] = fmaf(xsf[7*e+j], dj, z[e]);
      }
#pragma unroll
      for (int j=0;j<DIM;++j){
        const float dj = dW1s[DIM+j][k & 127];
#pragma unroll
        for (int e=0;e<16;++e) z[e] = fmaf(dsf[7*e+j], dj, z[e]);
      }
      const int kb = k>>3, ko = k&7;
#pragma unroll
      for (int e=0;e<16;++e){
        AbufD[e][8*(kb^(e&7)) + ko] = f2b(tanh_f(z[e]));
      }
    }
    PHASE_FENCE();   // Abuf writes before layer-2 reads

    // ---- layer 2 MFMA: [16 x 128] @ [128 x 128]
    f32x4 acc[8];
#pragma unroll
    for (int b=0;b<8;++b) acc[b] = f32x4{0.f,0.f,0.f,0.f};
#pragma unroll
    for (int s=0;s<4;++s){
      const int blk = 8*((4*s+g4)^rkey);
      bf16x8 A0 = *(const bf16x8*)&AbufD[R][blk];
#pragma unroll
      for (int t=0;t<8;++t)
        acc[t] = __builtin_amdgcn_mfma_f32_16x16x32_bf16(A0, as_bf(W2rD[s*8+t]), acc[t], 0,0,0);
    }
    PHASE_FENCE();   // Abuf reads before A' overwrite

    // ---- h2 = tanh(z2), restage A' (C layout: row e = 4*g4+reg, col = 16t+c)
#pragma unroll
    for (int t=0;t<8;++t){
      const int col = 16*t+c;
      const int cb = col>>3, co = col&7;
#pragma unroll
      for (int reg=0;reg<4;++reg){
        const int e = 4*g4+reg;
        const float h2 = tanh_f(acc[t][reg] + b2sD[col]);
        AbufD[e][8*(cb^(e&7)) + co] = f2b(h2);
      }
    }
    PHASE_FENCE();   // A' writes before layer-3 reads

    // ---- layer 3 MFMA: [16 x 128] @ [128 x 32(pad of 28)]
    f32x4 acc3[2];
    acc3[0]=f32x4{0.f,0.f,0.f,0.f}; acc3[1]=f32x4{0.f,0.f,0.f,0.f};
#pragma unroll
    for (int s=0;s<4;++s){
      const int blk = 8*((4*s+g4)^rkey);
      bf16x8 A0 = *(const bf16x8*)&AbufD[R][blk];
#pragma unroll
      for (int nt=0;nt<2;++nt)
        acc3[nt] = __builtin_amdgcn_mfma_f32_16x16x32_bf16(A0, as_bf(W3rD[s*2+nt]), acc3[nt], 0,0,0);
    }

    // ---- scatter raw
#pragma unroll
    for (int nt=0;nt<2;++nt){
      const int t = 16*nt+c;
      if (t < CHOL){
#pragma unroll
        for (int reg=0;reg<4;++reg) rawD[4*g4+reg][t] = acc3[nt][reg];
      }
    }
    PHASE_FENCE();   // rawD writes before L-build reads

    // ---- build L (softplus diagonal): 4 lanes/element, 7 entries each
#pragma unroll
    for (int m=0;m<7;++m){
      const int t = 7*sub + m;
      const float e0 = rawD[eL][t] + b3sD[t];
      const bool dg = (t==0)|(t==2)|(t==5)|(t==9)|(t==14)|(t==20)|(t==27);
      LbD[eL][t] = dg ? sp_f(e0) : e0;
    }
    PHASE_FENCE();

    // ---- w = L^T dq : lane covers c = sub, sub+4
    for (int cc = sub; cc < DIM; cc += 4){
      float wv = 0.f;
      for (int r = cc; r < DIM; ++r)
        wv = fmaf(LbD[eL][r*(r+1)/2 + cc], dsf[7*eL + r], wv);
      wdb[eL][cc] = wv;
    }
    PHASE_FENCE();

    // ---- tau += L w : lane covers i = sub, sub+4
    for (int i0 = sub; i0 < DIM; i0 += 4){
      float td = 0.f;
      for (int cc = 0; cc <= i0; ++cc)
        td = fmaf(LbD[eL][i0*(i0+1)/2 + cc], wdb[eL][cc], td);
      out[(long)(ebase+eL)*DIM + i0] += td;
    }
    PHASE_FENCE();   // tail reads before next-iter overwrites
  }
}

extern "C" void kernel_launch(void* const* d_in, const int* in_sizes, int n_in,
                              void* d_out, int out_size, void* d_ws, size_t ws_size,
                              hipStream_t stream) {
  const float* q   = (const float*)d_in[0];
  const float* dq  = (const float*)d_in[1];
  const float* ddq = (const float*)d_in[2];
  const float* mW1 = (const float*)d_in[3];
  const float* mb1 = (const float*)d_in[4];
  const float* mW2 = (const float*)d_in[5];
  const float* mb2 = (const float*)d_in[6];
  const float* mW3 = (const float*)d_in[7];
  const float* mb3 = (const float*)d_in[8];
  const float* dW1 = (const float*)d_in[9];
  const float* db1 = (const float*)d_in[10];
  const float* dW2 = (const float*)d_in[11];
  const float* db2 = (const float*)d_in[12];
  const float* dW3 = (const float*)d_in[13];
  const float* db3 = (const float*)d_in[14];
  const float* pW1 = (const float*)d_in[15];
  const float* pb1 = (const float*)d_in[16];
  const float* pw2 = (const float*)d_in[17];
  float* out = (float*)d_out;
  unsigned* wsu = (unsigned*)d_ws;

  hipLaunchKernelGGL(setup_frags, dim3(80), dim3(256), 0, stream, mW2, mW3, dW2, dW3, wsu);
  hipLaunchKernelGGL(kernA, dim3(GRID_A), dim3(64), 0, stream,
                     q, dq, ddq, mW1, mb1, mb2, mb3, pW1, pb1, pw2, (const unsigned*)wsu, out);
  hipLaunchKernelGGL(kernB, dim3(GRID_B), dim3(64), 0, stream,
                     q, dq, dW1, db1, db2, db3, (const unsigned*)wsu, out);
}

// Round 10
// 325.119 us; speedup vs baseline: 4.3744x; 1.1429x over previous
//
#include <hip/hip_runtime.h>

#define DIM 7
#define HID 128
#define CHOL 28

#define GRID_A 2048
#define ITER_A 16          // 2048 blocks * 4 elem * 16 iter = 131072
#define GRID_B 2048
#define ITER_B 4           // 2048 blocks * 16 elem * 4 iter = 131072

// sched_barrier mask: ALU|VALU|SALU|MFMA|VMEM may cross; DS blocked (per-wave phase ordering).
#define PHASE_FENCE() __builtin_amdgcn_sched_barrier(0x7F)

typedef float    f32x4  __attribute__((ext_vector_type(4)));
typedef short    bf16x8 __attribute__((ext_vector_type(8)));
typedef unsigned uint4v __attribute__((ext_vector_type(4)));

__device__ __forceinline__ float tanh_f(float x){ float e=__expf(2.f*x); return 1.f - 2.f/(e+1.f); }
__device__ __forceinline__ float sig_f(float x){ return 1.f/(1.f+__expf(-x)); }
__device__ __forceinline__ float sp_f(float x){ return fmaxf(x,0.f) + __logf(1.f+__expf(-fabsf(x))); }

__device__ __forceinline__ unsigned short f2b(float v){
  unsigned u = __float_as_uint(v);
  u += 0x7FFFu + ((u>>16)&1u);          // RNE to bf16
  return (unsigned short)(u>>16);
}
__device__ __forceinline__ bf16x8 as_bf(uint4v u){ union { uint4v a; bf16x8 f; } x; x.a=u; return x.f; }

// ---- ws layout (u32): [0,8192) W2frag ; [8192,10240) W3frag ; [10240,18432) dW2frag ;
//                       [18432,20480) dW3frag   (80 KB total)
// frag order: u32 idx = (frag_id*64 + lane)*4 + i2 ; B[k][col], k = 32s+8*(l>>4)+2*i2(+1), col = 16t+(l&15)
// (A-frags use the SAME (group,elem)->k map, so layer-2/3 are correct for any HW intra-lane k order.)
__global__ void setup_frags(const float* __restrict__ mW2, const float* __restrict__ mW3,
                            const float* __restrict__ dW2, const float* __restrict__ dW3,
                            unsigned* __restrict__ ws){
  int idx = blockIdx.x*256 + threadIdx.x;
  if (idx < 8192) {
    int i2 = idx&3, f = idx>>2, l = f&63, st = f>>6;
    int s = st>>3, t = st&7;
    int k = 32*s + 8*(l>>4) + 2*i2, col = 16*t + (l&15);
    unsigned short lo = f2b(mW2[k*HID+col]), hi = f2b(mW2[(k+1)*HID+col]);
    ws[idx] = (unsigned)lo | ((unsigned)hi<<16);
  } else if (idx < 10240) {
    int j = idx-8192; int i2=j&3, f=j>>2, l=f&63, st=f>>6;
    int s = st>>1, t = st&1;
    int k = 32*s + 8*(l>>4) + 2*i2, col = 16*t + (l&15);
    float v0 = (col<CHOL) ? mW3[k*CHOL+col] : 0.f;
    float v1 = (col<CHOL) ? mW3[(k+1)*CHOL+col] : 0.f;
    ws[idx] = (unsigned)f2b(v0) | ((unsigned)f2b(v1)<<16);
  } else if (idx < 18432) {
    int j = idx-10240; int i2=j&3, f=j>>2, l=f&63, st=f>>6;
    int s = st>>3, t = st&7;
    int k = 32*s + 8*(l>>4) + 2*i2, col = 16*t + (l&15);
    unsigned short lo = f2b(dW2[k*HID+col]), hi = f2b(dW2[(k+1)*HID+col]);
    ws[idx] = (unsigned)lo | ((unsigned)hi<<16);
  } else if (idx < 20480) {
    int j = idx-18432; int i2=j&3, f=j>>2, l=f&63, st=f>>6;
    int s = st>>1, t = st&1;
    int k = 32*s + 8*(l>>4) + 2*i2, col = 16*t + (l&15);
    float v0 = (col<CHOL) ? dW3[k*CHOL+col] : 0.f;
    float v1 = (col<CHOL) ? dW3[(k+1)*CHOL+col] : 0.f;
    ws[idx] = (unsigned)f2b(v0) | ((unsigned)f2b(v1)<<16);
  }
}

// ---------------- Kernel A: MFMA, fused layer-2+A'-build (reg-capped for 2 waves/SIMD) --------
// 1 wave/block, 4 elements/iter. Two 16x128 A tiles: rows 8e..8e+7 = [fwd, tan0..6] of element e.
// Abuf layout: [mt][row][k] bf16, 16B-block XOR swizzle: k-block kb stored at kb ^ (row&7).
// Layer-2 fused per col-tile t: 8-reg accumulator instead of 64 -> total regs <= 256.
__global__ __launch_bounds__(64, 2) void kernA(
    const float* __restrict__ q, const float* __restrict__ dq, const float* __restrict__ ddq,
    const float* __restrict__ mW1, const float* __restrict__ mb1,
    const float* __restrict__ mb2, const float* __restrict__ mb3,
    const float* __restrict__ pW1, const float* __restrict__ pb1, const float* __restrict__ pw2,
    const unsigned* __restrict__ ws, float* __restrict__ out)
{
  __shared__ __align__(16) unsigned short Abuf[2][16][HID];  // 8KB, reused for A'
  __shared__ float sbf[4][HID+8];                            // sigmoid(zp)*softplus(pw2), padded
  __shared__ float pW1s[DIM][HID+8];                         // pW1 staged, padded
  __shared__ float rawb[4][8][CHOL];
  __shared__ float b2s[HID];
  __shared__ float b3s[CHOL];
  __shared__ float Lbs[4][CHOL], dLss[4][CHOL], dfs[4][CHOL];
  __shared__ float gvp2[4][14];
  __shared__ float wbs[4][DIM], ubs[4][DIM], vss[4][DIM];

  const int lane = threadIdx.x;
  const int g4 = lane>>4, c = lane&15;
  const int R = lane&15, r7 = lane&7;

  b2s[lane] = mb2[lane]; b2s[lane+64] = mb2[lane+64];
  if (lane < CHOL) b3s[lane] = mb3[lane];
  for (int idx = lane; idx < DIM*HID; idx += 64) pW1s[idx>>7][idx&127] = pW1[idx];

  // iteration-invariant weights in registers
  float w1v0[DIM], w1v1[DIM], pw1v0[DIM], pw1v1[DIM];
#pragma unroll
  for (int j=0;j<DIM;++j){
    w1v0[j]=mW1[j*HID+lane];  w1v1[j]=mW1[j*HID+lane+64];
    pw1v0[j]=pW1[j*HID+lane]; pw1v1[j]=pW1[j*HID+lane+64];
  }
  const float b1v0=mb1[lane], b1v1=mb1[lane+64];
  const float pbv0=pb1[lane], pbv1=pb1[lane+64];
  const float sp0=sp_f(pw2[lane]), sp1=sp_f(pw2[lane+64]);

  // B-fragments: loop-invariant, resident in VGPRs (32+8 uint4v = 160 VGPRs)
  const uint4v* __restrict__ W2f = (const uint4v*)ws;
  const uint4v* __restrict__ W3f = (const uint4v*)(ws + 8192);
  uint4v W2r[32];
#pragma unroll
  for (int i=0;i<32;++i) W2r[i] = W2f[i*64 + lane];
  uint4v W3r[8];
#pragma unroll
  for (int i=0;i<8;++i)  W3r[i] = W3f[i*64 + lane];

  __syncthreads();   // prologue only (staged pW1s/b2s/b3s)

  for (int it=0; it<ITER_A; ++it){
    const int ebase = (it*GRID_A + (int)blockIdx.x)*4;

    // ---- phase 1: layer 1 + tangent seeds + sb
    const int kb0 = lane>>3, ko = lane&7;
#pragma unroll
    for (int e=0;e<4;++e){
      const float* qp = q + (long)(ebase+e)*DIM;
      float qv[DIM];
#pragma unroll
      for (int j=0;j<DIM;++j) qv[j]=qp[j];
      const int mt = e>>1, R0 = 8*(e&1);
      {
        float z1=b1v0, zp=pbv0;
#pragma unroll
        for (int j=0;j<DIM;++j){ z1=fmaf(qv[j],w1v0[j],z1); zp=fmaf(qv[j],pw1v0[j],zp); }
        float h1=tanh_f(z1), g1=1.f-h1*h1;
        Abuf[mt][R0][8*kb0 + ko] = f2b(h1);                      // row&7==0: kb^0
#pragma unroll
        for (int j=0;j<DIM;++j)
          Abuf[mt][R0+1+j][8*(kb0^(1+j)) + ko] = f2b(g1*w1v0[j]);
        sbf[e][lane] = sig_f(zp)*sp0;
      }
      {
        float z1=b1v1, zp=pbv1;
#pragma unroll
        for (int j=0;j<DIM;++j){ z1=fmaf(qv[j],w1v1[j],z1); zp=fmaf(qv[j],pw1v1[j],zp); }
        float h1=tanh_f(z1), g1=1.f-h1*h1;
        const int kb1 = kb0+8;
        Abuf[mt][R0][8*kb1 + ko] = f2b(h1);
#pragma unroll
        for (int j=0;j<DIM;++j)
          Abuf[mt][R0+1+j][8*(kb1^(1+j)) + ko] = f2b(g1*w1v1[j]);
        sbf[e][lane+64] = sig_f(zp)*sp1;
      }
    }
    PHASE_FENCE();   // Abuf/sbf writes before A-frag reads

    // ---- read all A-fragments (Abuf then free for in-place A' overwrite)
    bf16x8 Af0[4], Af1[4];
#pragma unroll
    for (int s=0;s<4;++s){
      const int blk = 8*((4*s+g4)^r7);
      Af0[s] = *(const bf16x8*)&Abuf[0][R][blk];
      Af1[s] = *(const bf16x8*)&Abuf[1][R][blk];
    }
    PHASE_FENCE();   // A-frag ds_reads issued before A' ds_writes (in-order DS pipe)

    // ---- fused layer-2 MFMA + h2 + A'-build, per col-tile t (8-reg live accumulator)
#pragma unroll
    for (int t=0;t<8;++t){
      f32x4 a0 = f32x4{0.f,0.f,0.f,0.f};
      f32x4 a1 = f32x4{0.f,0.f,0.f,0.f};
#pragma unroll
      for (int s=0;s<4;++s){
        bf16x8 B = as_bf(W2r[s*8+t]);
        a0 = __builtin_amdgcn_mfma_f32_16x16x32_bf16(Af0[s],B,a0,0,0,0);
        a1 = __builtin_amdgcn_mfma_f32_16x16x32_bf16(Af1[s],B,a1,0,0,0);
      }
      const int col = 16*t+c;
      const int cb = col>>3, co = col&7;
      // mt = 0
      {
        const float z2  = a0[0] + b2s[col];
        const float h2o = tanh_f(z2);                 // valid on even g4
        const float h2x = __shfl_xor(h2o, 16);
        const float h2  = (g4&1) ? h2x : h2o;
        const float g2  = 1.f - h2*h2;
#pragma unroll
        for (int reg=0;reg<4;++reg){
          const int Rr = 4*g4+reg;
          const int key = Rr&7;
          float v = g2*a0[reg];
          if (key==0) v = h2;
          Abuf[0][Rr][8*(cb^key) + co] = f2b(v);
        }
      }
      // mt = 1
      {
        const float z2  = a1[0] + b2s[col];
        const float h2o = tanh_f(z2);
        const float h2x = __shfl_xor(h2o, 16);
        const float h2  = (g4&1) ? h2x : h2o;
        const float g2  = 1.f - h2*h2;
#pragma unroll
        for (int reg=0;reg<4;++reg){
          const int Rr = 4*g4+reg;
          const int key = Rr&7;
          float v = g2*a1[reg];
          if (key==0) v = h2;
          Abuf[1][Rr][8*(cb^key) + co] = f2b(v);
        }
      }
    }
    PHASE_FENCE();   // A' writes before layer-3 reads

    // ---- layer 3 MFMA: [32 x 128] @ [128 x 32(pad of 28)], B in registers
    f32x4 acc3[2][2];
#pragma unroll
    for (int a=0;a<2;++a){ acc3[a][0]=f32x4{0.f,0.f,0.f,0.f}; acc3[a][1]=f32x4{0.f,0.f,0.f,0.f}; }
#pragma unroll
    for (int s=0;s<4;++s){
      const int blk = 8*((4*s+g4)^r7);
      bf16x8 A0 = *(const bf16x8*)&Abuf[0][R][blk];
      bf16x8 A1 = *(const bf16x8*)&Abuf[1][R][blk];
#pragma unroll
      for (int nt=0;nt<2;++nt){
        bf16x8 B = as_bf(W3r[s*2+nt]);
        acc3[0][nt] = __builtin_amdgcn_mfma_f32_16x16x32_bf16(A0,B,acc3[0][nt],0,0,0);
        acc3[1][nt] = __builtin_amdgcn_mfma_f32_16x16x32_bf16(A1,B,acc3[1][nt],0,0,0);
      }
    }

    // ---- gradV partials (VALU): element g4, slot c<14: i=c%7, half=c/7
    if (c < 14){
      const int iv = (c<7)? c : c-7;
      const int nb = (c<7)? 0 : 64;
      float gp = 0.f;
#pragma unroll 8
      for (int nn=0; nn<64; ++nn)
        gp = fmaf(pW1s[iv][nb+nn], sbf[g4][nb+nn], gp);
      gvp2[g4][c] = gp;
    }

    // ---- scatter raw to LDS
#pragma unroll
    for (int mt=0;mt<2;++mt){
      const int em = 2*mt + (g4>>1);
      const int rb = (g4&1)*4;
#pragma unroll
      for (int nt=0;nt<2;++nt){
        const int t = 16*nt+c;
        if (t < CHOL){
#pragma unroll
          for (int reg=0;reg<4;++reg) rawb[em][rb+reg][t] = acc3[mt][nt][reg];
        }
      }
    }
    PHASE_FENCE();   // rawb/gvp2 writes before tail reads

    // ---- tail: element em = g4, 16 lanes each
    float dqv[DIM];
    {
      const float* dqp = dq + (long)(ebase+g4)*DIM;
#pragma unroll
      for (int j=0;j<DIM;++j) dqv[j]=dqp[j];
    }
#pragma unroll
    for (int h=0;h<2;++h){
      const int t = c + 16*h;
      if (t < CHOL){
        const float e0 = rawb[g4][0][t] + b3s[t];
        const bool dg = (t==0)|(t==2)|(t==5)|(t==9)|(t==14)|(t==20)|(t==27);
        const float Lv = dg ? sp_f(e0) : e0;
        const float df = dg ? sig_f(e0) : 1.f;
        float s_=0.f;
#pragma unroll
        for (int j=0;j<DIM;++j) s_=fmaf(dqv[j], rawb[g4][1+j][t], s_);
        Lbs[g4][t]=Lv; dfs[g4][t]=df; dLss[g4][t]=df*s_;
      }
    }
    PHASE_FENCE();   // Lbs/dfs/dLss writes before reads
    if (c < DIM){
      const float* ddqp = ddq + (long)(ebase+g4)*DIM;
      float wv=0.f, uv=0.f, vv=0.f;
#pragma unroll
      for (int r=0;r<DIM;++r){
        if (r>=c){
          const int id=r*(r+1)/2+c;
          const float Lrc = Lbs[g4][id];
          wv=fmaf(Lrc,dqv[r],wv);
          uv=fmaf(Lrc,ddqp[r],uv);
          vv=fmaf(dLss[g4][id],dqv[r],vv);
        }
      }
      wbs[g4][c]=wv; ubs[g4][c]=uv; vss[g4][c]=vv;
    }
    PHASE_FENCE();   // wbs/ubs/vss writes before reads
    if (c < DIM){
      const int i=c;
      float t12=0.f;
#pragma unroll
      for (int c2=0;c2<DIM;++c2){
        if (c2<=i){
          const int id=i*(i+1)/2+c2;
          t12=fmaf(Lbs[g4][id], ubs[g4][c2]+vss[g4][c2], t12);
          t12=fmaf(dLss[g4][id], wbs[g4][c2], t12);
        }
      }
      const int TRt[CHOL]={0,1,1,2,2,2,3,3,3,3,4,4,4,4,4,5,5,5,5,5,5,6,6,6,6,6,6,6};
      const int TCt[CHOL]={0,0,1,0,1,2,0,1,2,3,0,1,2,3,4,0,1,2,3,4,5,0,1,2,3,4,5,6};
      float t3=0.f;
#pragma unroll
      for (int t=0;t<CHOL;++t)
        t3=fmaf(rawb[g4][1+i][t]*dfs[g4][t], dqv[TRt[t]]*wbs[g4][TCt[t]], t3);
      out[(long)(ebase+g4)*DIM + i] = t12 - t3 + gvp2[g4][i] + gvp2[g4][7+i];
    }
    PHASE_FENCE();   // iteration boundary: tail reads before next phase-1 overwrites
  }
}

// ---------------- Kernel B: damping, MFMA version (unchanged from round 9) ----------------
__global__ __launch_bounds__(64, 1) void kernB(
    const float* __restrict__ q, const float* __restrict__ dq,
    const float* __restrict__ dW1, const float* __restrict__ db1,
    const float* __restrict__ db2, const float* __restrict__ db3,
    const unsigned* __restrict__ ws, float* __restrict__ out)
{
  __shared__ __align__(16) unsigned short AbufD[16][HID];  // 4KB, reused for A'
  __shared__ float dW1s[2*DIM][HID];                        // 7KB (layer-1 weights)
  __shared__ float xsf[112+8], dsf[112+8];                  // q/dq rows, flat [e*7+j]
  __shared__ float rawD[16][CHOL];
  __shared__ float LbD[16][CHOL];
  __shared__ float wdb[16][8];
  __shared__ float b2sD[HID];
  __shared__ float b3sD[CHOL];

  const int lane = threadIdx.x;
  const int g4 = lane>>4, c = lane&15;
  const int R = lane&15, rkey = lane&7;
  const int eL = lane>>2, sub = lane&3;

  b2sD[lane] = db2[lane]; b2sD[lane+64] = db2[lane+64];
  if (lane < CHOL) b3sD[lane] = db3[lane];
  for (int idx = lane; idx < 2*DIM*HID; idx += 64) dW1s[idx>>7][idx&127] = dW1[idx];
  const float b1v0 = db1[lane], b1v1 = db1[lane+64];

  const uint4v* __restrict__ W2fD = (const uint4v*)(ws + 10240);
  const uint4v* __restrict__ W3fD = (const uint4v*)(ws + 18432);
  uint4v W2rD[32];
#pragma unroll
  for (int i=0;i<32;++i) W2rD[i] = W2fD[i*64 + lane];
  uint4v W3rD[8];
#pragma unroll
  for (int i=0;i<8;++i)  W3rD[i] = W3fD[i*64 + lane];

  __syncthreads();   // prologue only

  for (int it=0; it<ITER_B; ++it){
    const int ebase = (it*GRID_B + (int)blockIdx.x)*16;

    // ---- stage x = [q,dq] rows (16 elements x 7)
    for (int idx=lane; idx<112; idx+=64){
      xsf[idx] = q[(long)ebase*DIM + idx];
      dsf[idx] = dq[(long)ebase*DIM + idx];
    }
    PHASE_FENCE();

    // ---- layer 1: z = [q,dq] @ dW1 + b1 ; stage h1 into swizzled Abuf
#pragma unroll
    for (int h=0; h<2; ++h){
      const int k = lane + 64*h;
      float z[16];
#pragma unroll
      for (int e=0;e<16;++e) z[e] = h ? b1v1 : b1v0;
#pragma unroll
      for (int j=0;j<DIM;++j){
        const float dj = dW1s[j][k & 127];
#pragma unroll
        for (int e=0;e<16;++e) z[e] = fmaf(xsf[7*e+j], dj, z[e]);
      }
#pragma unroll
      for (int j=0;j<DIM;++j){
        const float dj = dW1s[DIM+j][k & 127];
#pragma unroll
        for (int e=0;e<16;++e) z[e] = fmaf(dsf[7*e+j], dj, z[e]);
      }
      const int kb = k>>3, ko = k&7;
#pragma unroll
      for (int e=0;e<16;++e){
        AbufD[e][8*(kb^(e&7)) + ko] = f2b(tanh_f(z[e]));
      }
    }
    PHASE_FENCE();   // Abuf writes before layer-2 reads

    // ---- layer 2 MFMA: [16 x 128] @ [128 x 128]
    f32x4 acc[8];
#pragma unroll
    for (int b=0;b<8;++b) acc[b] = f32x4{0.f,0.f,0.f,0.f};
#pragma unroll
    for (int s=0;s<4;++s){
      const int blk = 8*((4*s+g4)^rkey);
      bf16x8 A0 = *(const bf16x8*)&AbufD[R][blk];
#pragma unroll
      for (int t=0;t<8;++t)
        acc[t] = __builtin_amdgcn_mfma_f32_16x16x32_bf16(A0, as_bf(W2rD[s*8+t]), acc[t], 0,0,0);
    }
    PHASE_FENCE();   // Abuf reads before A' overwrite

    // ---- h2 = tanh(z2), restage A' (C layout: row e = 4*g4+reg, col = 16t+c)
#pragma unroll
    for (int t=0;t<8;++t){
      const int col = 16*t+c;
      const int cb = col>>3, co = col&7;
#pragma unroll
      for (int reg=0;reg<4;++reg){
        const int e = 4*g4+reg;
        const float h2 = tanh_f(acc[t][reg] + b2sD[col]);
        AbufD[e][8*(cb^(e&7)) + co] = f2b(h2);
      }
    }
    PHASE_FENCE();   // A' writes before layer-3 reads

    // ---- layer 3 MFMA: [16 x 128] @ [128 x 32(pad of 28)]
    f32x4 acc3[2];
    acc3[0]=f32x4{0.f,0.f,0.f,0.f}; acc3[1]=f32x4{0.f,0.f,0.f,0.f};
#pragma unroll
    for (int s=0;s<4;++s){
      const int blk = 8*((4*s+g4)^rkey);
      bf16x8 A0 = *(const bf16x8*)&AbufD[R][blk];
#pragma unroll
      for (int nt=0;nt<2;++nt)
        acc3[nt] = __builtin_amdgcn_mfma_f32_16x16x32_bf16(A0, as_bf(W3rD[s*2+nt]), acc3[nt], 0,0,0);
    }

    // ---- scatter raw
#pragma unroll
    for (int nt=0;nt<2;++nt){
      const int t = 16*nt+c;
      if (t < CHOL){
#pragma unroll
        for (int reg=0;reg<4;++reg) rawD[4*g4+reg][t] = acc3[nt][reg];
      }
    }
    PHASE_FENCE();   // rawD writes before L-build reads

    // ---- build L (softplus diagonal): 4 lanes/element, 7 entries each
#pragma unroll
    for (int m=0;m<7;++m){
      const int t = 7*sub + m;
      const float e0 = rawD[eL][t] + b3sD[t];
      const bool dg = (t==0)|(t==2)|(t==5)|(t==9)|(t==14)|(t==20)|(t==27);
      LbD[eL][t] = dg ? sp_f(e0) : e0;
    }
    PHASE_FENCE();

    // ---- w = L^T dq : lane covers c = sub, sub+4
    for (int cc = sub; cc < DIM; cc += 4){
      float wv = 0.f;
      for (int r = cc; r < DIM; ++r)
        wv = fmaf(LbD[eL][r*(r+1)/2 + cc], dsf[7*eL + r], wv);
      wdb[eL][cc] = wv;
    }
    PHASE_FENCE();

    // ---- tau += L w : lane covers i = sub, sub+4
    for (int i0 = sub; i0 < DIM; i0 += 4){
      float td = 0.f;
      for (int cc = 0; cc <= i0; ++cc)
        td = fmaf(LbD[eL][i0*(i0+1)/2 + cc], wdb[eL][cc], td);
      out[(long)(ebase+eL)*DIM + i0] += td;
    }
    PHASE_FENCE();   // tail reads before next-iter overwrites
  }
}

extern "C" void kernel_launch(void* const* d_in, const int* in_sizes, int n_in,
                              void* d_out, int out_size, void* d_ws, size_t ws_size,
                              hipStream_t stream) {
  const float* q   = (const float*)d_in[0];
  const float* dq  = (const float*)d_in[1];
  const float* ddq = (const float*)d_in[2];
  const float* mW1 = (const float*)d_in[3];
  const float* mb1 = (const float*)d_in[4];
  const float* mW2 = (const float*)d_in[5];
  const float* mb2 = (const float*)d_in[6];
  const float* mW3 = (const float*)d_in[7];
  const float* mb3 = (const float*)d_in[8];
  const float* dW1 = (const float*)d_in[9];
  const float* db1 = (const float*)d_in[10];
  const float* dW2 = (const float*)d_in[11];
  const float* db2 = (const float*)d_in[12];
  const float* dW3 = (const float*)d_in[13];
  const float* db3 = (const float*)d_in[14];
  const float* pW1 = (const float*)d_in[15];
  const float* pb1 = (const float*)d_in[16];
  const float* pw2 = (const float*)d_in[17];
  float* out = (float*)d_out;
  unsigned* wsu = (unsigned*)d_ws;

  hipLaunchKernelGGL(setup_frags, dim3(80), dim3(256), 0, stream, mW2, mW3, dW2, dW3, wsu);
  hipLaunchKernelGGL(kernA, dim3(GRID_A), dim3(64), 0, stream,
                     q, dq, ddq, mW1, mb1, mb2, mb3, pW1, pb1, pw2, (const unsigned*)wsu, out);
  hipLaunchKernelGGL(kernB, dim3(GRID_B), dim3(64), 0, stream,
                     q, dq, dW1, db1, db2, db3, (const unsigned*)wsu, out);
}

// Round 11
// 262.068 us; speedup vs baseline: 5.4268x; 1.2406x over previous
//
#include <hip/hip_runtime.h>

#define DIM 7
#define HID 128
#define CHOL 28

#define GRID_A 512
#define ITER_A 16          // 512 blocks * 4 waves * 4 elem * 16 iter = 131072
#define GRID_B 2048
#define ITER_B 4           // 2048 blocks * 16 elem * 4 iter = 131072

// sched_barrier mask: ALU|VALU|SALU|MFMA|VMEM may cross; DS blocked (per-wave phase ordering).
#define PHASE_FENCE() __builtin_amdgcn_sched_barrier(0x7F)

typedef float    f32x4  __attribute__((ext_vector_type(4)));
typedef short    bf16x8 __attribute__((ext_vector_type(8)));
typedef unsigned uint4v __attribute__((ext_vector_type(4)));

__device__ __forceinline__ float tanh_f(float x){ float e=__expf(2.f*x); return 1.f - 2.f/(e+1.f); }
__device__ __forceinline__ float sig_f(float x){ return 1.f/(1.f+__expf(-x)); }
__device__ __forceinline__ float sp_f(float x){ return fmaxf(x,0.f) + __logf(1.f+__expf(-fabsf(x))); }

__device__ __forceinline__ unsigned short f2b(float v){
  unsigned u = __float_as_uint(v);
  u += 0x7FFFu + ((u>>16)&1u);          // RNE to bf16
  return (unsigned short)(u>>16);
}
__device__ __forceinline__ bf16x8 as_bf(uint4v u){ union { uint4v a; bf16x8 f; } x; x.a=u; return x.f; }

// ---- ws layout (u32): [0,8192) W2frag ; [8192,10240) W3frag ; [10240,18432) dW2frag ;
//                       [18432,20480) dW3frag   (80 KB total)
// frag order: u32 idx = (frag_id*64 + lane)*4 + i2 ; B[k][col], k = 32s+8*(l>>4)+2*i2(+1), col = 16t+(l&15)
// (A-frags use the SAME (group,elem)->k map, so layer-2/3 are correct for any HW intra-lane k order.)
__global__ void setup_frags(const float* __restrict__ mW2, const float* __restrict__ mW3,
                            const float* __restrict__ dW2, const float* __restrict__ dW3,
                            unsigned* __restrict__ ws){
  int idx = blockIdx.x*256 + threadIdx.x;
  if (idx < 8192) {
    int i2 = idx&3, f = idx>>2, l = f&63, st = f>>6;
    int s = st>>3, t = st&7;
    int k = 32*s + 8*(l>>4) + 2*i2, col = 16*t + (l&15);
    unsigned short lo = f2b(mW2[k*HID+col]), hi = f2b(mW2[(k+1)*HID+col]);
    ws[idx] = (unsigned)lo | ((unsigned)hi<<16);
  } else if (idx < 10240) {
    int j = idx-8192; int i2=j&3, f=j>>2, l=f&63, st=f>>6;
    int s = st>>1, t = st&1;
    int k = 32*s + 8*(l>>4) + 2*i2, col = 16*t + (l&15);
    float v0 = (col<CHOL) ? mW3[k*CHOL+col] : 0.f;
    float v1 = (col<CHOL) ? mW3[(k+1)*CHOL+col] : 0.f;
    ws[idx] = (unsigned)f2b(v0) | ((unsigned)f2b(v1)<<16);
  } else if (idx < 18432) {
    int j = idx-10240; int i2=j&3, f=j>>2, l=f&63, st=f>>6;
    int s = st>>3, t = st&7;
    int k = 32*s + 8*(l>>4) + 2*i2, col = 16*t + (l&15);
    unsigned short lo = f2b(dW2[k*HID+col]), hi = f2b(dW2[(k+1)*HID+col]);
    ws[idx] = (unsigned)lo | ((unsigned)hi<<16);
  } else if (idx < 20480) {
    int j = idx-18432; int i2=j&3, f=j>>2, l=f&63, st=f>>6;
    int s = st>>1, t = st&1;
    int k = 32*s + 8*(l>>4) + 2*i2, col = 16*t + (l&15);
    float v0 = (col<CHOL) ? dW3[k*CHOL+col] : 0.f;
    float v1 = (col<CHOL) ? dW3[(k+1)*CHOL+col] : 0.f;
    ws[idx] = (unsigned)f2b(v0) | ((unsigned)f2b(v1)<<16);
  }
}

// ---------------- Kernel A: 4-wave blocks; W2 in VGPRs, W3 in shared LDS (no spill) ----------
// Each wave owns 4 elements/iter (two 16x128 A tiles, rows 8e..8e+7 = [fwd, tan0..6]).
// Abuf layout: [wid][mt][row][k] bf16, 16B-block XOR swizzle: k-block kb stored at kb ^ (row&7).
// Shared read-only LDS: pW1s, b2s, b3s, W3lds. Per-iter LDS all [wid]-indexed -> wave-local
// fences only (PHASE_FENCE); __syncthreads only after prologue. LDS ~76KB -> 2 blocks/CU
// = 8 waves/CU = 2 waves/SIMD, with ~235 regs/wave demand (W2r 128 + Af 16 + acc3 16 + misc).
__global__ __launch_bounds__(256, 2) void kernA(
    const float* __restrict__ q, const float* __restrict__ dq, const float* __restrict__ ddq,
    const float* __restrict__ mW1, const float* __restrict__ mb1,
    const float* __restrict__ mb2, const float* __restrict__ mb3,
    const float* __restrict__ pW1, const float* __restrict__ pb1, const float* __restrict__ pw2,
    const unsigned* __restrict__ ws, float* __restrict__ out)
{
  __shared__ __align__(16) unsigned short Abuf[4][2][16][HID];  // 32KB, per-wave, reused for A'
  __shared__ __align__(16) uint4v W3lds[512];                   // 8KB: 8 frags x 64 lanes
  __shared__ float sbf[4][4][HID+8];                            // per-wave sb, padded
  __shared__ float pW1s[DIM][HID+8];                            // shared pW1, padded
  __shared__ float rawb[4][4][8][CHOL];
  __shared__ float b2s[HID];
  __shared__ float b3s[CHOL];
  __shared__ float Lbs[4][4][CHOL], dLss[4][4][CHOL], dfs[4][4][CHOL];
  __shared__ float gvp2[4][4][14];
  __shared__ float wbs[4][4][DIM], ubs[4][4][DIM], vss[4][4][DIM];

  const int tid  = threadIdx.x;
  const int wid  = tid>>6;
  const int lane = tid&63;
  const int g4 = lane>>4, c = lane&15;
  const int R = lane&15, r7 = lane&7;

  // ---- prologue staging (block-shared)
  if (tid < HID) b2s[tid] = mb2[tid];
  if (tid >= HID && tid < HID+CHOL) b3s[tid-HID] = mb3[tid-HID];
  for (int idx = tid; idx < DIM*HID; idx += 256) pW1s[idx>>7][idx&127] = pW1[idx];
  for (int idx = tid; idx < 512; idx += 256) W3lds[idx] = ((const uint4v*)(ws + 8192))[idx];

  // iteration-invariant weights in registers (per lane; identical across waves)
  float w1v0[DIM], w1v1[DIM], pw1v0[DIM], pw1v1[DIM];
#pragma unroll
  for (int j=0;j<DIM;++j){
    w1v0[j]=mW1[j*HID+lane];  w1v1[j]=mW1[j*HID+lane+64];
    pw1v0[j]=pW1[j*HID+lane]; pw1v1[j]=pW1[j*HID+lane+64];
  }
  const float b1v0=mb1[lane], b1v1=mb1[lane+64];
  const float pbv0=pb1[lane], pbv1=pb1[lane+64];
  const float sp0=sp_f(pw2[lane]), sp1=sp_f(pw2[lane+64]);

  // W2 B-fragments: loop-invariant, resident in VGPRs (32 uint4v = 128 VGPRs)
  const uint4v* __restrict__ W2f = (const uint4v*)ws;
  uint4v W2r[32];
#pragma unroll
  for (int i=0;i<32;++i) W2r[i] = W2f[i*64 + lane];

  __syncthreads();   // prologue only (shared pW1s/b2s/b3s/W3lds)

  for (int it=0; it<ITER_A; ++it){
    const int ebase = (it*GRID_A + (int)blockIdx.x)*16 + wid*4;

    // ---- phase 1: layer 1 + tangent seeds + sb
    const int kb0 = lane>>3, ko = lane&7;
#pragma unroll
    for (int e=0;e<4;++e){
      const float* qp = q + (long)(ebase+e)*DIM;
      float qv[DIM];
#pragma unroll
      for (int j=0;j<DIM;++j) qv[j]=qp[j];
      const int mt = e>>1, R0 = 8*(e&1);
      {
        float z1=b1v0, zp=pbv0;
#pragma unroll
        for (int j=0;j<DIM;++j){ z1=fmaf(qv[j],w1v0[j],z1); zp=fmaf(qv[j],pw1v0[j],zp); }
        float h1=tanh_f(z1), g1=1.f-h1*h1;
        Abuf[wid][mt][R0][8*kb0 + ko] = f2b(h1);                 // row&7==0: kb^0
#pragma unroll
        for (int j=0;j<DIM;++j)
          Abuf[wid][mt][R0+1+j][8*(kb0^(1+j)) + ko] = f2b(g1*w1v0[j]);
        sbf[wid][e][lane] = sig_f(zp)*sp0;
      }
      {
        float z1=b1v1, zp=pbv1;
#pragma unroll
        for (int j=0;j<DIM;++j){ z1=fmaf(qv[j],w1v1[j],z1); zp=fmaf(qv[j],pw1v1[j],zp); }
        float h1=tanh_f(z1), g1=1.f-h1*h1;
        const int kb1 = kb0+8;
        Abuf[wid][mt][R0][8*kb1 + ko] = f2b(h1);
#pragma unroll
        for (int j=0;j<DIM;++j)
          Abuf[wid][mt][R0+1+j][8*(kb1^(1+j)) + ko] = f2b(g1*w1v1[j]);
        sbf[wid][e][lane+64] = sig_f(zp)*sp1;
      }
    }
    PHASE_FENCE();   // Abuf/sbf writes before A-frag reads

    // ---- read all A-fragments (Abuf then free for in-place A' overwrite)
    bf16x8 Af0[4], Af1[4];
#pragma unroll
    for (int s=0;s<4;++s){
      const int blk = 8*((4*s+g4)^r7);
      Af0[s] = *(const bf16x8*)&Abuf[wid][0][R][blk];
      Af1[s] = *(const bf16x8*)&Abuf[wid][1][R][blk];
    }
    PHASE_FENCE();   // A-frag ds_reads issued before A' ds_writes (in-order DS pipe)

    // ---- fused layer-2 MFMA + h2 + A'-build, per col-tile t (8-reg live accumulator)
#pragma unroll
    for (int t=0;t<8;++t){
      f32x4 a0 = f32x4{0.f,0.f,0.f,0.f};
      f32x4 a1 = f32x4{0.f,0.f,0.f,0.f};
#pragma unroll
      for (int s=0;s<4;++s){
        bf16x8 B = as_bf(W2r[s*8+t]);
        a0 = __builtin_amdgcn_mfma_f32_16x16x32_bf16(Af0[s],B,a0,0,0,0);
        a1 = __builtin_amdgcn_mfma_f32_16x16x32_bf16(Af1[s],B,a1,0,0,0);
      }
      const int col = 16*t+c;
      const int cb = col>>3, co = col&7;
      // mt = 0
      {
        const float z2  = a0[0] + b2s[col];
        const float h2o = tanh_f(z2);                 // valid on even g4
        const float h2x = __shfl_xor(h2o, 16);
        const float h2  = (g4&1) ? h2x : h2o;
        const float g2  = 1.f - h2*h2;
#pragma unroll
        for (int reg=0;reg<4;++reg){
          const int Rr = 4*g4+reg;
          const int key = Rr&7;
          float v = g2*a0[reg];
          if (key==0) v = h2;
          Abuf[wid][0][Rr][8*(cb^key) + co] = f2b(v);
        }
      }
      // mt = 1
      {
        const float z2  = a1[0] + b2s[col];
        const float h2o = tanh_f(z2);
        const float h2x = __shfl_xor(h2o, 16);
        const float h2  = (g4&1) ? h2x : h2o;
        const float g2  = 1.f - h2*h2;
#pragma unroll
        for (int reg=0;reg<4;++reg){
          const int Rr = 4*g4+reg;
          const int key = Rr&7;
          float v = g2*a1[reg];
          if (key==0) v = h2;
          Abuf[wid][1][Rr][8*(cb^key) + co] = f2b(v);
        }
      }
    }
    PHASE_FENCE();   // A' writes before layer-3 reads

    // ---- layer 3 MFMA: [32 x 128] @ [128 x 32(pad of 28)], B from shared LDS
    f32x4 acc3[2][2];
#pragma unroll
    for (int a=0;a<2;++a){ acc3[a][0]=f32x4{0.f,0.f,0.f,0.f}; acc3[a][1]=f32x4{0.f,0.f,0.f,0.f}; }
#pragma unroll
    for (int s=0;s<4;++s){
      const int blk = 8*((4*s+g4)^r7);
      bf16x8 A0 = *(const bf16x8*)&Abuf[wid][0][R][blk];
      bf16x8 A1 = *(const bf16x8*)&Abuf[wid][1][R][blk];
#pragma unroll
      for (int nt=0;nt<2;++nt){
        bf16x8 B = as_bf(W3lds[(s*2+nt)*64 + lane]);
        acc3[0][nt] = __builtin_amdgcn_mfma_f32_16x16x32_bf16(A0,B,acc3[0][nt],0,0,0);
        acc3[1][nt] = __builtin_amdgcn_mfma_f32_16x16x32_bf16(A1,B,acc3[1][nt],0,0,0);
      }
    }

    // ---- gradV partials (VALU): element g4, slot c<14: i=c%7, half=c/7
    if (c < 14){
      const int iv = (c<7)? c : c-7;
      const int nb = (c<7)? 0 : 64;
      float gp = 0.f;
#pragma unroll 8
      for (int nn=0; nn<64; ++nn)
        gp = fmaf(pW1s[iv][nb+nn], sbf[wid][g4][nb+nn], gp);
      gvp2[wid][g4][c] = gp;
    }

    // ---- scatter raw to LDS
#pragma unroll
    for (int mt=0;mt<2;++mt){
      const int em = 2*mt + (g4>>1);
      const int rb = (g4&1)*4;
#pragma unroll
      for (int nt=0;nt<2;++nt){
        const int t = 16*nt+c;
        if (t < CHOL){
#pragma unroll
          for (int reg=0;reg<4;++reg) rawb[wid][em][rb+reg][t] = acc3[mt][nt][reg];
        }
      }
    }
    PHASE_FENCE();   // rawb/gvp2 writes before tail reads

    // ---- tail: element em = g4, 16 lanes each
    float dqv[DIM];
    {
      const float* dqp = dq + (long)(ebase+g4)*DIM;
#pragma unroll
      for (int j=0;j<DIM;++j) dqv[j]=dqp[j];
    }
#pragma unroll
    for (int h=0;h<2;++h){
      const int t = c + 16*h;
      if (t < CHOL){
        const float e0 = rawb[wid][g4][0][t] + b3s[t];
        const bool dg = (t==0)|(t==2)|(t==5)|(t==9)|(t==14)|(t==20)|(t==27);
        const float Lv = dg ? sp_f(e0) : e0;
        const float df = dg ? sig_f(e0) : 1.f;
        float s_=0.f;
#pragma unroll
        for (int j=0;j<DIM;++j) s_=fmaf(dqv[j], rawb[wid][g4][1+j][t], s_);
        Lbs[wid][g4][t]=Lv; dfs[wid][g4][t]=df; dLss[wid][g4][t]=df*s_;
      }
    }
    PHASE_FENCE();   // Lbs/dfs/dLss writes before reads
    if (c < DIM){
      const float* ddqp = ddq + (long)(ebase+g4)*DIM;
      float wv=0.f, uv=0.f, vv=0.f;
#pragma unroll
      for (int r=0;r<DIM;++r){
        if (r>=c){
          const int id=r*(r+1)/2+c;
          const float Lrc = Lbs[wid][g4][id];
          wv=fmaf(Lrc,dqv[r],wv);
          uv=fmaf(Lrc,ddqp[r],uv);
          vv=fmaf(dLss[wid][g4][id],dqv[r],vv);
        }
      }
      wbs[wid][g4][c]=wv; ubs[wid][g4][c]=uv; vss[wid][g4][c]=vv;
    }
    PHASE_FENCE();   // wbs/ubs/vss writes before reads
    if (c < DIM){
      const int i=c;
      float t12=0.f;
#pragma unroll
      for (int c2=0;c2<DIM;++c2){
        if (c2<=i){
          const int id=i*(i+1)/2+c2;
          t12=fmaf(Lbs[wid][g4][id], ubs[wid][g4][c2]+vss[wid][g4][c2], t12);
          t12=fmaf(dLss[wid][g4][id], wbs[wid][g4][c2], t12);
        }
      }
      const int TRt[CHOL]={0,1,1,2,2,2,3,3,3,3,4,4,4,4,4,5,5,5,5,5,5,6,6,6,6,6,6,6};
      const int TCt[CHOL]={0,0,1,0,1,2,0,1,2,3,0,1,2,3,4,0,1,2,3,4,5,0,1,2,3,4,5,6};
      float t3=0.f;
#pragma unroll
      for (int t=0;t<CHOL;++t)
        t3=fmaf(rawb[wid][g4][1+i][t]*dfs[wid][g4][t], dqv[TRt[t]]*wbs[wid][g4][TCt[t]], t3);
      out[(long)(ebase+g4)*DIM + i] = t12 - t3 + gvp2[wid][g4][i] + gvp2[wid][g4][7+i];
    }
    PHASE_FENCE();   // iteration boundary: tail reads before next phase-1 overwrites
  }
}

// ---------------- Kernel B: damping, MFMA version (unchanged from round 9) ----------------
__global__ __launch_bounds__(64, 1) void kernB(
    const float* __restrict__ q, const float* __restrict__ dq,
    const float* __restrict__ dW1, const float* __restrict__ db1,
    const float* __restrict__ db2, const float* __restrict__ db3,
    const unsigned* __restrict__ ws, float* __restrict__ out)
{
  __shared__ __align__(16) unsigned short AbufD[16][HID];  // 4KB, reused for A'
  __shared__ float dW1s[2*DIM][HID];                        // 7KB (layer-1 weights)
  __shared__ float xsf[112+8], dsf[112+8];                  // q/dq rows, flat [e*7+j]
  __shared__ float rawD[16][CHOL];
  __shared__ float LbD[16][CHOL];
  __shared__ float wdb[16][8];
  __shared__ float b2sD[HID];
  __shared__ float b3sD[CHOL];

  const int lane = threadIdx.x;
  const int g4 = lane>>4, c = lane&15;
  const int R = lane&15, rkey = lane&7;
  const int eL = lane>>2, sub = lane&3;

  b2sD[lane] = db2[lane]; b2sD[lane+64] = db2[lane+64];
  if (lane < CHOL) b3sD[lane] = db3[lane];
  for (int idx = lane; idx < 2*DIM*HID; idx += 64) dW1s[idx>>7][idx&127] = dW1[idx];
  const float b1v0 = db1[lane], b1v1 = db1[lane+64];

  const uint4v* __restrict__ W2fD = (const uint4v*)(ws + 10240);
  const uint4v* __restrict__ W3fD = (const uint4v*)(ws + 18432);
  uint4v W2rD[32];
#pragma unroll
  for (int i=0;i<32;++i) W2rD[i] = W2fD[i*64 + lane];
  uint4v W3rD[8];
#pragma unroll
  for (int i=0;i<8;++i)  W3rD[i] = W3fD[i*64 + lane];

  __syncthreads();   // prologue only

  for (int it=0; it<ITER_B; ++it){
    const int ebase = (it*GRID_B + (int)blockIdx.x)*16;

    // ---- stage x = [q,dq] rows (16 elements x 7)
    for (int idx=lane; idx<112; idx+=64){
      xsf[idx] = q[(long)ebase*DIM + idx];
      dsf[idx] = dq[(long)ebase*DIM + idx];
    }
    PHASE_FENCE();

    // ---- layer 1: z = [q,dq] @ dW1 + b1 ; stage h1 into swizzled Abuf
#pragma unroll
    for (int h=0; h<2; ++h){
      const int k = lane + 64*h;
      float z[16];
#pragma unroll
      for (int e=0;e<16;++e) z[e] = h ? b1v1 : b1v0;
#pragma unroll
      for (int j=0;j<DIM;++j){
        const float dj = dW1s[j][k & 127];
#pragma unroll
        for (int e=0;e<16;++e) z[e] = fmaf(xsf[7*e+j], dj, z[e]);
      }
#pragma unroll
      for (int j=0;j<DIM;++j){
        const float dj = dW1s[DIM+j][k & 127];
#pragma unroll
        for (int e=0;e<16;++e) z[e] = fmaf(dsf[7*e+j], dj, z[e]);
      }
      const int kb = k>>3, ko = k&7;
#pragma unroll
      for (int e=0;e<16;++e){
        AbufD[e][8*(kb^(e&7)) + ko] = f2b(tanh_f(z[e]));
      }
    }
    PHASE_FENCE();   // Abuf writes before layer-2 reads

    // ---- layer 2 MFMA: [16 x 128] @ [128 x 128]
    f32x4 acc[8];
#pragma unroll
    for (int b=0;b<8;++b) acc[b] = f32x4{0.f,0.f,0.f,0.f};
#pragma unroll
    for (int s=0;s<4;++s){
      const int blk = 8*((4*s+g4)^rkey);
      bf16x8 A0 = *(const bf16x8*)&AbufD[R][blk];
#pragma unroll
      for (int t=0;t<8;++t)
        acc[t] = __builtin_amdgcn_mfma_f32_16x16x32_bf16(A0, as_bf(W2rD[s*8+t]), acc[t], 0,0,0);
    }
    PHASE_FENCE();   // Abuf reads before A' overwrite

    // ---- h2 = tanh(z2), restage A' (C layout: row e = 4*g4+reg, col = 16t+c)
#pragma unroll
    for (int t=0;t<8;++t){
      const int col = 16*t+c;
      const int cb = col>>3, co = col&7;
#pragma unroll
      for (int reg=0;reg<4;++reg){
        const int e = 4*g4+reg;
        const float h2 = tanh_f(acc[t][reg] + b2sD[col]);
        AbufD[e][8*(cb^(e&7)) + co] = f2b(h2);
      }
    }
    PHASE_FENCE();   // A' writes before layer-3 reads

    // ---- layer 3 MFMA: [16 x 128] @ [128 x 32(pad of 28)]
    f32x4 acc3[2];
    acc3[0]=f32x4{0.f,0.f,0.f,0.f}; acc3[1]=f32x4{0.f,0.f,0.f,0.f};
#pragma unroll
    for (int s=0;s<4;++s){
      const int blk = 8*((4*s+g4)^rkey);
      bf16x8 A0 = *(const bf16x8*)&AbufD[R][blk];
#pragma unroll
      for (int nt=0;nt<2;++nt)
        acc3[nt] = __builtin_amdgcn_mfma_f32_16x16x32_bf16(A0, as_bf(W3rD[s*2+nt]), acc3[nt], 0,0,0);
    }

    // ---- scatter raw
#pragma unroll
    for (int nt=0;nt<2;++nt){
      const int t = 16*nt+c;
      if (t < CHOL){
#pragma unroll
        for (int reg=0;reg<4;++reg) rawD[4*g4+reg][t] = acc3[nt][reg];
      }
    }
    PHASE_FENCE();   // rawD writes before L-build reads

    // ---- build L (softplus diagonal): 4 lanes/element, 7 entries each
#pragma unroll
    for (int m=0;m<7;++m){
      const int t = 7*sub + m;
      const float e0 = rawD[eL][t] + b3sD[t];
      const bool dg = (t==0)|(t==2)|(t==5)|(t==9)|(t==14)|(t==20)|(t==27);
      LbD[eL][t] = dg ? sp_f(e0) : e0;
    }
    PHASE_FENCE();

    // ---- w = L^T dq : lane covers c = sub, sub+4
    for (int cc = sub; cc < DIM; cc += 4){
      float wv = 0.f;
      for (int r = cc; r < DIM; ++r)
        wv = fmaf(LbD[eL][r*(r+1)/2 + cc], dsf[7*eL + r], wv);
      wdb[eL][cc] = wv;
    }
    PHASE_FENCE();

    // ---- tau += L w : lane covers i = sub, sub+4
    for (int i0 = sub; i0 < DIM; i0 += 4){
      float td = 0.f;
      for (int cc = 0; cc <= i0; ++cc)
        td = fmaf(LbD[eL][i0*(i0+1)/2 + cc], wdb[eL][cc], td);
      out[(long)(ebase+eL)*DIM + i0] += td;
    }
    PHASE_FENCE();   // tail reads before next-iter overwrites
  }
}

extern "C" void kernel_launch(void* const* d_in, const int* in_sizes, int n_in,
                              void* d_out, int out_size, void* d_ws, size_t ws_size,
                              hipStream_t stream) {
  const float* q   = (const float*)d_in[0];
  const float* dq  = (const float*)d_in[1];
  const float* ddq = (const float*)d_in[2];
  const float* mW1 = (const float*)d_in[3];
  const float* mb1 = (const float*)d_in[4];
  const float* mW2 = (const float*)d_in[5];
  const float* mb2 = (const float*)d_in[6];
  const float* mW3 = (const float*)d_in[7];
  const float* mb3 = (const float*)d_in[8];
  const float* dW1 = (const float*)d_in[9];
  const float* db1 = (const float*)d_in[10];
  const float* dW2 = (const float*)d_in[11];
  const float* db2 = (const float*)d_in[12];
  const float* dW3 = (const float*)d_in[13];
  const float* db3 = (const float*)d_in[14];
  const float* pW1 = (const float*)d_in[15];
  const float* pb1 = (const float*)d_in[16];
  const float* pw2 = (const float*)d_in[17];
  float* out = (float*)d_out;
  unsigned* wsu = (unsigned*)d_ws;

  hipLaunchKernelGGL(setup_frags, dim3(80), dim3(256), 0, stream, mW2, mW3, dW2, dW3, wsu);
  hipLaunchKernelGGL(kernA, dim3(GRID_A), dim3(256), 0, stream,
                     q, dq, ddq, mW1, mb1, mb2, mb3, pW1, pb1, pw2, (const unsigned*)wsu, out);
  hipLaunchKernelGGL(kernB, dim3(GRID_B), dim3(64), 0, stream,
                     q, dq, dW1, db1, db2, db3, (const unsigned*)wsu, out);
}

// Round 12
// 233.808 us; speedup vs baseline: 6.0828x; 1.1209x over previous
//
#include <hip/hip_runtime.h>

#define DIM 7
#define HID 128
#define CHOL 28

#define GRID_A 256
#define ITER_A 16          // 256 blocks * 8 waves * 4 elem * 16 iter = 131072
#define GRID_B 256
#define ITER_B 4           // 256 blocks * 8 waves * 16 elem * 4 iter = 131072

// sched_barrier mask: ALU|VALU|SALU|MFMA|VMEM may cross; DS blocked (per-wave phase ordering).
#define PHASE_FENCE() __builtin_amdgcn_sched_barrier(0x7F)

typedef float    f32x4  __attribute__((ext_vector_type(4)));
typedef short    bf16x8 __attribute__((ext_vector_type(8)));
typedef unsigned uint4v __attribute__((ext_vector_type(4)));

__device__ __forceinline__ float tanh_f(float x){ float e=__expf(2.f*x); return 1.f - 2.f/(e+1.f); }
__device__ __forceinline__ float sig_f(float x){ return 1.f/(1.f+__expf(-x)); }
__device__ __forceinline__ float sp_f(float x){ return fmaxf(x,0.f) + __logf(1.f+__expf(-fabsf(x))); }

__device__ __forceinline__ unsigned short f2b(float v){
  unsigned u = __float_as_uint(v);
  u += 0x7FFFu + ((u>>16)&1u);          // RNE to bf16
  return (unsigned short)(u>>16);
}
__device__ __forceinline__ float b2f(unsigned short v){
  return __uint_as_float(((unsigned)v)<<16);
}
__device__ __forceinline__ bf16x8 as_bf(uint4v u){ union { uint4v a; bf16x8 f; } x; x.a=u; return x.f; }

// ---- ws layout (u32): [0,8192) W2frag ; [8192,10240) W3frag ; [10240,18432) dW2frag ;
//                       [18432,20480) dW3frag   (80 KB total)
// frag order: u32 idx = (frag_id*64 + lane)*4 + i2 ; B[k][col], k = 32s+8*(l>>4)+2*i2(+1), col = 16t+(l&15)
// (A-frags use the SAME (group,elem)->k map, so layer-2/3 are correct for any HW intra-lane k order.)
__global__ void setup_frags(const float* __restrict__ mW2, const float* __restrict__ mW3,
                            const float* __restrict__ dW2, const float* __restrict__ dW3,
                            unsigned* __restrict__ ws){
  int idx = blockIdx.x*256 + threadIdx.x;
  if (idx < 8192) {
    int i2 = idx&3, f = idx>>2, l = f&63, st = f>>6;
    int s = st>>3, t = st&7;
    int k = 32*s + 8*(l>>4) + 2*i2, col = 16*t + (l&15);
    unsigned short lo = f2b(mW2[k*HID+col]), hi = f2b(mW2[(k+1)*HID+col]);
    ws[idx] = (unsigned)lo | ((unsigned)hi<<16);
  } else if (idx < 10240) {
    int j = idx-8192; int i2=j&3, f=j>>2, l=f&63, st=f>>6;
    int s = st>>1, t = st&1;
    int k = 32*s + 8*(l>>4) + 2*i2, col = 16*t + (l&15);
    float v0 = (col<CHOL) ? mW3[k*CHOL+col] : 0.f;
    float v1 = (col<CHOL) ? mW3[(k+1)*CHOL+col] : 0.f;
    ws[idx] = (unsigned)f2b(v0) | ((unsigned)f2b(v1)<<16);
  } else if (idx < 18432) {
    int j = idx-10240; int i2=j&3, f=j>>2, l=f&63, st=f>>6;
    int s = st>>3, t = st&7;
    int k = 32*s + 8*(l>>4) + 2*i2, col = 16*t + (l&15);
    unsigned short lo = f2b(dW2[k*HID+col]), hi = f2b(dW2[(k+1)*HID+col]);
    ws[idx] = (unsigned)lo | ((unsigned)hi<<16);
  } else if (idx < 20480) {
    int j = idx-18432; int i2=j&3, f=j>>2, l=f&63, st=f>>6;
    int s = st>>1, t = st&1;
    int k = 32*s + 8*(l>>4) + 2*i2, col = 16*t + (l&15);
    float v0 = (col<CHOL) ? dW3[k*CHOL+col] : 0.f;
    float v1 = (col<CHOL) ? dW3[(k+1)*CHOL+col] : 0.f;
    ws[idx] = (unsigned)f2b(v0) | ((unsigned)f2b(v1)<<16);
  }
}

// ---------------- Kernel A: 8-wave blocks; W2+W3 in block-shared LDS (no spill) -------------
// Each wave owns 4 elements/iter (two 16x128 A tiles, rows 8e..8e+7 = [fwd, tan0..6]).
// Abuf: [wid][mt][row][k] bf16, 16B-block XOR swizzle: k-block kb stored at kb ^ (row&7).
// ~146KB LDS -> 1 block/CU = 8 waves/CU = 2 waves/SIMD, ~130 regs/wave honest (no scratch).
__global__ __launch_bounds__(512, 2) void kernA(
    const float* __restrict__ q, const float* __restrict__ dq, const float* __restrict__ ddq,
    const float* __restrict__ mW1, const float* __restrict__ mb1,
    const float* __restrict__ mb2, const float* __restrict__ mb3,
    const float* __restrict__ pW1, const float* __restrict__ pb1, const float* __restrict__ pw2,
    const unsigned* __restrict__ ws, float* __restrict__ out)
{
  __shared__ __align__(16) unsigned short Abuf[8][2][16][HID];  // 64KB, per-wave, reused for A'
  __shared__ __align__(16) uint4v W2lds[2048];                  // 32KB: 32 frags x 64 lanes
  __shared__ __align__(16) uint4v W3lds[512];                   // 8KB:   8 frags x 64 lanes
  __shared__ unsigned short sbf[8][4][HID];                     // 8.5KB, bf16
  __shared__ unsigned short rawb[8][4][8][CHOL];                // 14.3KB, bf16
  __shared__ float pW1s[DIM][HID+8];                            // shared pW1, padded
  __shared__ float b2s[HID];
  __shared__ float b3s[CHOL];
  __shared__ float Lbs[8][4][CHOL], dLss[8][4][CHOL], dfs[8][4][CHOL];
  __shared__ float gvp2[8][4][14];
  __shared__ float wbs[8][4][DIM], ubs[8][4][DIM], vss[8][4][DIM];

  const int tid  = threadIdx.x;
  const int wid  = tid>>6;
  const int lane = tid&63;
  const int g4 = lane>>4, c = lane&15;
  const int R = lane&15, r7 = lane&7;

  // ---- prologue staging (block-shared)
  if (tid < HID) b2s[tid] = mb2[tid];
  if (tid >= HID && tid < HID+CHOL) b3s[tid-HID] = mb3[tid-HID];
  for (int idx = tid; idx < DIM*HID; idx += 512) pW1s[idx>>7][idx&127] = pW1[idx];
  for (int idx = tid; idx < 2048; idx += 512) W2lds[idx] = ((const uint4v*)ws)[idx];
  for (int idx = tid; idx < 512;  idx += 512) W3lds[idx] = ((const uint4v*)(ws + 8192))[idx];

  // iteration-invariant weights in registers (per lane; identical across waves)
  float w1v0[DIM], w1v1[DIM], pw1v0[DIM], pw1v1[DIM];
#pragma unroll
  for (int j=0;j<DIM;++j){
    w1v0[j]=mW1[j*HID+lane];  w1v1[j]=mW1[j*HID+lane+64];
    pw1v0[j]=pW1[j*HID+lane]; pw1v1[j]=pW1[j*HID+lane+64];
  }
  const float b1v0=mb1[lane], b1v1=mb1[lane+64];
  const float pbv0=pb1[lane], pbv1=pb1[lane+64];
  const float sp0=sp_f(pw2[lane]), sp1=sp_f(pw2[lane+64]);

  __syncthreads();   // prologue only (shared staging)

  for (int it=0; it<ITER_A; ++it){
    const int ebase = (it*GRID_A + (int)blockIdx.x)*32 + wid*4;

    // ---- phase 1: layer 1 + tangent seeds + sb
    const int kb0 = lane>>3, ko = lane&7;
#pragma unroll
    for (int e=0;e<4;++e){
      const float* qp = q + (long)(ebase+e)*DIM;
      float qv[DIM];
#pragma unroll
      for (int j=0;j<DIM;++j) qv[j]=qp[j];
      const int mt = e>>1, R0 = 8*(e&1);
      {
        float z1=b1v0, zp=pbv0;
#pragma unroll
        for (int j=0;j<DIM;++j){ z1=fmaf(qv[j],w1v0[j],z1); zp=fmaf(qv[j],pw1v0[j],zp); }
        float h1=tanh_f(z1), g1=1.f-h1*h1;
        Abuf[wid][mt][R0][8*kb0 + ko] = f2b(h1);                 // row&7==0: kb^0
#pragma unroll
        for (int j=0;j<DIM;++j)
          Abuf[wid][mt][R0+1+j][8*(kb0^(1+j)) + ko] = f2b(g1*w1v0[j]);
        sbf[wid][e][lane] = f2b(sig_f(zp)*sp0);
      }
      {
        float z1=b1v1, zp=pbv1;
#pragma unroll
        for (int j=0;j<DIM;++j){ z1=fmaf(qv[j],w1v1[j],z1); zp=fmaf(qv[j],pw1v1[j],zp); }
        float h1=tanh_f(z1), g1=1.f-h1*h1;
        const int kb1 = kb0+8;
        Abuf[wid][mt][R0][8*kb1 + ko] = f2b(h1);
#pragma unroll
        for (int j=0;j<DIM;++j)
          Abuf[wid][mt][R0+1+j][8*(kb1^(1+j)) + ko] = f2b(g1*w1v1[j]);
        sbf[wid][e][lane+64] = f2b(sig_f(zp)*sp1);
      }
    }
    PHASE_FENCE();   // Abuf/sbf writes before A-frag reads

    // ---- read all A-fragments (Abuf then free for in-place A' overwrite)
    bf16x8 Af0[4], Af1[4];
#pragma unroll
    for (int s=0;s<4;++s){
      const int blk = 8*((4*s+g4)^r7);
      Af0[s] = *(const bf16x8*)&Abuf[wid][0][R][blk];
      Af1[s] = *(const bf16x8*)&Abuf[wid][1][R][blk];
    }
    PHASE_FENCE();   // A-frag ds_reads issued before A' ds_writes (in-order DS pipe)

    // ---- fused layer-2 MFMA + h2 + A'-build, per col-tile t (8-reg live accumulator)
#pragma unroll
    for (int t=0;t<8;++t){
      f32x4 a0 = f32x4{0.f,0.f,0.f,0.f};
      f32x4 a1 = f32x4{0.f,0.f,0.f,0.f};
#pragma unroll
      for (int s=0;s<4;++s){
        bf16x8 B = as_bf(W2lds[(s*8+t)*64 + lane]);
        a0 = __builtin_amdgcn_mfma_f32_16x16x32_bf16(Af0[s],B,a0,0,0,0);
        a1 = __builtin_amdgcn_mfma_f32_16x16x32_bf16(Af1[s],B,a1,0,0,0);
      }
      const int col = 16*t+c;
      const int cb = col>>3, co = col&7;
      // mt = 0
      {
        const float z2  = a0[0] + b2s[col];
        const float h2o = tanh_f(z2);                 // valid on even g4
        const float h2x = __shfl_xor(h2o, 16);
        const float h2  = (g4&1) ? h2x : h2o;
        const float g2  = 1.f - h2*h2;
#pragma unroll
        for (int reg=0;reg<4;++reg){
          const int Rr = 4*g4+reg;
          const int key = Rr&7;
          float v = g2*a0[reg];
          if (key==0) v = h2;
          Abuf[wid][0][Rr][8*(cb^key) + co] = f2b(v);
        }
      }
      // mt = 1
      {
        const float z2  = a1[0] + b2s[col];
        const float h2o = tanh_f(z2);
        const float h2x = __shfl_xor(h2o, 16);
        const float h2  = (g4&1) ? h2x : h2o;
        const float g2  = 1.f - h2*h2;
#pragma unroll
        for (int reg=0;reg<4;++reg){
          const int Rr = 4*g4+reg;
          const int key = Rr&7;
          float v = g2*a1[reg];
          if (key==0) v = h2;
          Abuf[wid][1][Rr][8*(cb^key) + co] = f2b(v);
        }
      }
    }
    PHASE_FENCE();   // A' writes before layer-3 reads

    // ---- layer 3 MFMA: [32 x 128] @ [128 x 32(pad of 28)], B from shared LDS
    f32x4 acc3[2][2];
#pragma unroll
    for (int a=0;a<2;++a){ acc3[a][0]=f32x4{0.f,0.f,0.f,0.f}; acc3[a][1]=f32x4{0.f,0.f,0.f,0.f}; }
#pragma unroll
    for (int s=0;s<4;++s){
      const int blk = 8*((4*s+g4)^r7);
      bf16x8 A0 = *(const bf16x8*)&Abuf[wid][0][R][blk];
      bf16x8 A1 = *(const bf16x8*)&Abuf[wid][1][R][blk];
#pragma unroll
      for (int nt=0;nt<2;++nt){
        bf16x8 B = as_bf(W3lds[(s*2+nt)*64 + lane]);
        acc3[0][nt] = __builtin_amdgcn_mfma_f32_16x16x32_bf16(A0,B,acc3[0][nt],0,0,0);
        acc3[1][nt] = __builtin_amdgcn_mfma_f32_16x16x32_bf16(A1,B,acc3[1][nt],0,0,0);
      }
    }

    // ---- gradV partials (VALU): element g4, slot c<14: i=c%7, half=c/7
    if (c < 14){
      const int iv = (c<7)? c : c-7;
      const int nb = (c<7)? 0 : 64;
      float gp = 0.f;
#pragma unroll 8
      for (int nn=0; nn<64; ++nn)
        gp = fmaf(pW1s[iv][nb+nn], b2f(sbf[wid][g4][nb+nn]), gp);
      gvp2[wid][g4][c] = gp;
    }

    // ---- scatter raw to LDS (bf16)
#pragma unroll
    for (int mt=0;mt<2;++mt){
      const int em = 2*mt + (g4>>1);
      const int rb = (g4&1)*4;
#pragma unroll
      for (int nt=0;nt<2;++nt){
        const int t = 16*nt+c;
        if (t < CHOL){
#pragma unroll
          for (int reg=0;reg<4;++reg) rawb[wid][em][rb+reg][t] = f2b(acc3[mt][nt][reg]);
        }
      }
    }
    PHASE_FENCE();   // rawb/gvp2 writes before tail reads

    // ---- tail: element em = g4, 16 lanes each
    float dqv[DIM];
    {
      const float* dqp = dq + (long)(ebase+g4)*DIM;
#pragma unroll
      for (int j=0;j<DIM;++j) dqv[j]=dqp[j];
    }
#pragma unroll
    for (int h=0;h<2;++h){
      const int t = c + 16*h;
      if (t < CHOL){
        const float e0 = b2f(rawb[wid][g4][0][t]) + b3s[t];
        const bool dg = (t==0)|(t==2)|(t==5)|(t==9)|(t==14)|(t==20)|(t==27);
        const float Lv = dg ? sp_f(e0) : e0;
        const float df = dg ? sig_f(e0) : 1.f;
        float s_=0.f;
#pragma unroll
        for (int j=0;j<DIM;++j) s_=fmaf(dqv[j], b2f(rawb[wid][g4][1+j][t]), s_);
        Lbs[wid][g4][t]=Lv; dfs[wid][g4][t]=df; dLss[wid][g4][t]=df*s_;
      }
    }
    PHASE_FENCE();   // Lbs/dfs/dLss writes before reads
    if (c < DIM){
      const float* ddqp = ddq + (long)(ebase+g4)*DIM;
      float wv=0.f, uv=0.f, vv=0.f;
#pragma unroll
      for (int r=0;r<DIM;++r){
        if (r>=c){
          const int id=r*(r+1)/2+c;
          const float Lrc = Lbs[wid][g4][id];
          wv=fmaf(Lrc,dqv[r],wv);
          uv=fmaf(Lrc,ddqp[r],uv);
          vv=fmaf(dLss[wid][g4][id],dqv[r],vv);
        }
      }
      wbs[wid][g4][c]=wv; ubs[wid][g4][c]=uv; vss[wid][g4][c]=vv;
    }
    PHASE_FENCE();   // wbs/ubs/vss writes before reads
    if (c < DIM){
      const int i=c;
      float t12=0.f;
#pragma unroll
      for (int c2=0;c2<DIM;++c2){
        if (c2<=i){
          const int id=i*(i+1)/2+c2;
          t12=fmaf(Lbs[wid][g4][id], ubs[wid][g4][c2]+vss[wid][g4][c2], t12);
          t12=fmaf(dLss[wid][g4][id], wbs[wid][g4][c2], t12);
        }
      }
      const int TRt[CHOL]={0,1,1,2,2,2,3,3,3,3,4,4,4,4,4,5,5,5,5,5,5,6,6,6,6,6,6,6};
      const int TCt[CHOL]={0,0,1,0,1,2,0,1,2,3,0,1,2,3,4,0,1,2,3,4,5,0,1,2,3,4,5,6};
      float t3=0.f;
#pragma unroll
      for (int t=0;t<CHOL;++t)
        t3=fmaf(b2f(rawb[wid][g4][1+i][t])*dfs[wid][g4][t], dqv[TRt[t]]*wbs[wid][g4][TCt[t]], t3);
      out[(long)(ebase+g4)*DIM + i] = t12 - t3 + gvp2[wid][g4][i] + gvp2[wid][g4][7+i];
    }
    PHASE_FENCE();   // iteration boundary: tail reads before next phase-1 overwrites
  }
}

// ---------------- Kernel B: damping, 8-wave blocks, dW2/dW3 in shared LDS ----------------
__global__ __launch_bounds__(512, 2) void kernB(
    const float* __restrict__ q, const float* __restrict__ dq,
    const float* __restrict__ dW1, const float* __restrict__ db1,
    const float* __restrict__ db2, const float* __restrict__ db3,
    const unsigned* __restrict__ ws, float* __restrict__ out)
{
  __shared__ __align__(16) unsigned short AbufD[8][16][HID];   // 32KB, per-wave, reused for A'
  __shared__ __align__(16) uint4v dW2lds[2048];                // 32KB
  __shared__ __align__(16) uint4v dW3lds[512];                 // 8KB
  __shared__ float dW1s[2*DIM][HID];                           // 7KB (layer-1 weights)
  __shared__ float xsf[8][112+8], dsf[8][112+8];               // per-wave q/dq rows
  __shared__ float rawD[8][16][CHOL];
  __shared__ float LbD[8][16][CHOL];
  __shared__ float wdb[8][16][8];
  __shared__ float b2sD[HID];
  __shared__ float b3sD[CHOL];

  const int tid  = threadIdx.x;
  const int wid  = tid>>6;
  const int lane = tid&63;
  const int g4 = lane>>4, c = lane&15;
  const int R = lane&15, rkey = lane&7;
  const int eL = lane>>2, sub = lane&3;

  if (tid < HID) b2sD[tid] = db2[tid];
  if (tid >= HID && tid < HID+CHOL) b3sD[tid-HID] = db3[tid-HID];
  for (int idx = tid; idx < 2*DIM*HID; idx += 512) dW1s[idx>>7][idx&127] = dW1[idx];
  for (int idx = tid; idx < 2048; idx += 512) dW2lds[idx] = ((const uint4v*)(ws + 10240))[idx];
  for (int idx = tid; idx < 512;  idx += 512) dW3lds[idx] = ((const uint4v*)(ws + 18432))[idx];
  const float b1v0 = db1[lane], b1v1 = db1[lane+64];

  __syncthreads();   // prologue only

  for (int it=0; it<ITER_B; ++it){
    const int ebase = (it*GRID_B + (int)blockIdx.x)*128 + wid*16;

    // ---- stage x = [q,dq] rows (16 elements x 7, per wave)
    for (int idx=lane; idx<112; idx+=64){
      xsf[wid][idx] = q[(long)ebase*DIM + idx];
      dsf[wid][idx] = dq[(long)ebase*DIM + idx];
    }
    PHASE_FENCE();

    // ---- layer 1: z = [q,dq] @ dW1 + b1 ; stage h1 into swizzled Abuf
#pragma unroll
    for (int h=0; h<2; ++h){
      const int k = lane + 64*h;
      float z[16];
#pragma unroll
      for (int e=0;e<16;++e) z[e] = h ? b1v1 : b1v0;
#pragma unroll
      for (int j=0;j<DIM;++j){
        const float dj = dW1s[j][k & 127];
#pragma unroll
        for (int e=0;e<16;++e) z[e] = fmaf(xsf[wid][7*e+j], dj, z[e]);
      }
#pragma unroll
      for (int j=0;j<DIM;++j){
        const float dj = dW1s[DIM+j][k & 127];
#pragma unroll
        for (int e=0;e<16;++e) z[e] = fmaf(dsf[wid][7*e+j], dj, z[e]);
      }
      const int kb = k>>3, ko = k&7;
#pragma unroll
      for (int e=0;e<16;++e){
        AbufD[wid][e][8*(kb^(e&7)) + ko] = f2b(tanh_f(z[e]));
      }
    }
    PHASE_FENCE();   // Abuf writes before layer-2 reads

    // ---- layer 2 MFMA: [16 x 128] @ [128 x 128]
    f32x4 acc[8];
#pragma unroll
    for (int b=0;b<8;++b) acc[b] = f32x4{0.f,0.f,0.f,0.f};
#pragma unroll
    for (int s=0;s<4;++s){
      const int blk = 8*((4*s+g4)^rkey);
      bf16x8 A0 = *(const bf16x8*)&AbufD[wid][R][blk];
#pragma unroll
      for (int t=0;t<8;++t)
        acc[t] = __builtin_amdgcn_mfma_f32_16x16x32_bf16(A0, as_bf(dW2lds[(s*8+t)*64+lane]), acc[t], 0,0,0);
    }
    PHASE_FENCE();   // Abuf reads before A' overwrite

    // ---- h2 = tanh(z2), restage A' (C layout: row e = 4*g4+reg, col = 16t+c)
#pragma unroll
    for (int t=0;t<8;++t){
      const int col = 16*t+c;
      const int cb = col>>3, co = col&7;
#pragma unroll
      for (int reg=0;reg<4;++reg){
        const int e = 4*g4+reg;
        const float h2 = tanh_f(acc[t][reg] + b2sD[col]);
        AbufD[wid][e][8*(cb^(e&7)) + co] = f2b(h2);
      }
    }
    PHASE_FENCE();   // A' writes before layer-3 reads

    // ---- layer 3 MFMA: [16 x 128] @ [128 x 32(pad of 28)]
    f32x4 acc3[2];
    acc3[0]=f32x4{0.f,0.f,0.f,0.f}; acc3[1]=f32x4{0.f,0.f,0.f,0.f};
#pragma unroll
    for (int s=0;s<4;++s){
      const int blk = 8*((4*s+g4)^rkey);
      bf16x8 A0 = *(const bf16x8*)&AbufD[wid][R][blk];
#pragma unroll
      for (int nt=0;nt<2;++nt)
        acc3[nt] = __builtin_amdgcn_mfma_f32_16x16x32_bf16(A0, as_bf(dW3lds[(s*2+nt)*64+lane]), acc3[nt], 0,0,0);
    }

    // ---- scatter raw
#pragma unroll
    for (int nt=0;nt<2;++nt){
      const int t = 16*nt+c;
      if (t < CHOL){
#pragma unroll
        for (int reg=0;reg<4;++reg) rawD[wid][4*g4+reg][t] = acc3[nt][reg];
      }
    }
    PHASE_FENCE();   // rawD writes before L-build reads

    // ---- build L (softplus diagonal): 4 lanes/element, 7 entries each
#pragma unroll
    for (int m=0;m<7;++m){
      const int t = 7*sub + m;
      const float e0 = rawD[wid][eL][t] + b3sD[t];
      const bool dg = (t==0)|(t==2)|(t==5)|(t==9)|(t==14)|(t==20)|(t==27);
      LbD[wid][eL][t] = dg ? sp_f(e0) : e0;
    }
    PHASE_FENCE();

    // ---- w = L^T dq : lane covers c = sub, sub+4
    for (int cc = sub; cc < DIM; cc += 4){
      float wv = 0.f;
      for (int r = cc; r < DIM; ++r)
        wv = fmaf(LbD[wid][eL][r*(r+1)/2 + cc], dsf[wid][7*eL + r], wv);
      wdb[wid][eL][cc] = wv;
    }
    PHASE_FENCE();

    // ---- tau += L w : lane covers i = sub, sub+4
    for (int i0 = sub; i0 < DIM; i0 += 4){
      float td = 0.f;
      for (int cc = 0; cc <= i0; ++cc)
        td = fmaf(LbD[wid][eL][i0*(i0+1)/2 + cc], wdb[wid][eL][cc], td);
      out[(long)(ebase+eL)*DIM + i0] += td;
    }
    PHASE_FENCE();   // tail reads before next-iter overwrites
  }
}

extern "C" void kernel_launch(void* const* d_in, const int* in_sizes, int n_in,
                              void* d_out, int out_size, void* d_ws, size_t ws_size,
                              hipStream_t stream) {
  const float* q   = (const float*)d_in[0];
  const float* dq  = (const float*)d_in[1];
  const float* ddq = (const float*)d_in[2];
  const float* mW1 = (const float*)d_in[3];
  const float* mb1 = (const float*)d_in[4];
  const float* mW2 = (const float*)d_in[5];
  const float* mb2 = (const float*)d_in[6];
  const float* mW3 = (const float*)d_in[7];
  const float* mb3 = (const float*)d_in[8];
  const float* dW1 = (const float*)d_in[9];
  const float* db1 = (const float*)d_in[10];
  const float* dW2 = (const float*)d_in[11];
  const float* db2 = (const float*)d_in[12];
  const float* dW3 = (const float*)d_in[13];
  const float* db3 = (const float*)d_in[14];
  const float* pW1 = (const float*)d_in[15];
  const float* pb1 = (const float*)d_in[16];
  const float* pw2 = (const float*)d_in[17];
  float* out = (float*)d_out;
  unsigned* wsu = (unsigned*)d_ws;

  hipLaunchKernelGGL(setup_frags, dim3(80), dim3(256), 0, stream, mW2, mW3, dW2, dW3, wsu);
  hipLaunchKernelGGL(kernA, dim3(GRID_A), dim3(512), 0, stream,
                     q, dq, ddq, mW1, mb1, mb2, mb3, pW1, pb1, pw2, (const unsigned*)wsu, out);
  hipLaunchKernelGGL(kernB, dim3(GRID_B), dim3(512), 0, stream,
                     q, dq, dW1, db1, db2, db3, (const unsigned*)wsu, out);
}